// Round 1
// baseline (1216.090 us; speedup 1.0000x reference)
//
#include <hip/hip_runtime.h>

#define HH 512
#define WW 512
#define HW_ 262144
#define NIMG 16
#define MK 2048
#define CAPB 4096

static constexpr size_t OFF_B1    = 16777216;   // 16MB
static constexpr size_t OFF_B2    = 33554432;   // 32MB
static constexpr size_t OFF_SMALL = 50331648;   // 48MB
// regions inside buffer A (free after smw is computed):
static constexpr size_t OFF_HIST = 0;           // 16*65536*4 = 4MB
static constexpr size_t OFF_SEL  = 4194304;     // 16*2048*4
static constexpr size_t OFF_BND  = 4325376;     // 16*4096*8
static constexpr size_t OFF_PX   = 4849664;
static constexpr size_t OFF_PY   = 4980736;
static constexpr size_t OFF_WXp  = 5111808;
static constexpr size_t OFF_WYp  = 5242880;
static constexpr size_t OFF_LG   = 5373952;
static constexpr size_t OFF_SL   = 5505024;
static constexpr size_t OFF_R    = 5636096;

// ---------- helpers ----------
__device__ __forceinline__ unsigned fmap(float f) {
  unsigned u = __float_as_uint(f);
  return (u & 0x80000000u) ? ~u : (u | 0x80000000u);
}
__device__ __forceinline__ float funmap(unsigned u) {
  return __uint_as_float((u & 0x80000000u) ? (u ^ 0x80000000u) : ~u);
}

template<int B>
__device__ __forceinline__ float brsum(float v, float* red) {
  int t = threadIdx.x;
  red[t] = v; __syncthreads();
  for (int s = B >> 1; s > 0; s >>= 1) {
    if (t < s) red[t] += red[t + s];
    __syncthreads();
  }
  float r = red[0]; __syncthreads();
  return r;
}
template<int B>
__device__ __forceinline__ float brmax(float v, float* red) {
  int t = threadIdx.x;
  red[t] = v; __syncthreads();
  for (int s = B >> 1; s > 0; s >>= 1) {
    if (t < s) red[t] = fmaxf(red[t], red[t + s]);
    __syncthreads();
  }
  float r = red[0]; __syncthreads();
  return r;
}

// gaussian (25 taps, normalized), slot 25 = scratch sum
__device__ __forceinline__ void make_g25(float* g) {
  int t = threadIdx.x;
  if (t < 25) {
    float x = -1.0f + (float)t * (2.0f / 24.0f);
    g[t] = expf(-(x * x) / 0.5f);
  }
  __syncthreads();
  if (t == 0) {
    float s = 0.0f;
    for (int k = 0; k < 25; k++) s += g[k];
    g[25] = s;
  }
  __syncthreads();
  if (t < 25) g[t] = g[t] / g[25];
  __syncthreads();
}
// coverage weights (51 taps, unnormalized)
__device__ __forceinline__ void make_w51(float* wc) {
  int t = threadIdx.x;
  if (t < 51) {
    float x = -2.0f + (float)t * (4.0f / 50.0f);
    wc[t] = expf(-x * x);
  }
  __syncthreads();
}

// ---------- softmax ----------
__global__ void k_max(const float* __restrict__ x, unsigned* mxb) {
  int img = blockIdx.x >> 6, blk = blockIdx.x & 63;
  const float* p = x + (size_t)img * HW_ + blk * 4096;
  float m = -3.4e38f;
  for (int i = threadIdx.x; i < 4096; i += 256) m = fmaxf(m, p[i]);
  __shared__ float red[256];
  m = brmax<256>(m, red);
  if (threadIdx.x == 0) atomicMax(&mxb[img], fmap(m));
}

__global__ void k_expsum(const float* __restrict__ x, float* kp,
                         const unsigned* mxb, float* sume) {
  int img = blockIdx.x >> 6, blk = blockIdx.x & 63;
  float mx = funmap(mxb[img]);
  size_t o = (size_t)img * HW_ + blk * 4096;
  float s = 0.0f;
  for (int i = threadIdx.x; i < 4096; i += 256) {
    float e = expf(x[o + i] - mx);
    kp[o + i] = e; s += e;
  }
  __shared__ float red[256];
  s = brsum<256>(s, red);
  if (threadIdx.x == 0) atomicAdd(&sume[img], s);
}

__global__ void k_norm(float* kp, const float* sume) {
  int t = blockIdx.x * 256 + threadIdx.x;
  int img = t >> 18;
  kp[t] = kp[t] / sume[img];
}

// ---------- matchability convs ----------
// horizontal valid conv (asymmetric-pad bug): cols [12,499] else 0
__global__ void k_hvalid(const float* __restrict__ kp, float* out) {
  __shared__ float g[26];
  make_g25(g);
  int t = blockIdx.x * 256 + threadIdx.x;
  int rem = t & (HW_ - 1); int j = rem & 511;
  float v = 0.0f;
  if (j >= 12 && j <= 499) {
    const float* row = kp + (t - j);
    for (int d = 0; d < 25; d++) v += g[d] * row[j - 12 + d];
  }
  out[t] = v;
}

// standard zero-padded horizontal conv on has_depth
__global__ void k_hstd(const float* __restrict__ hd, float* out) {
  __shared__ float g[26];
  make_g25(g);
  int t = blockIdx.x * 256 + threadIdx.x;
  int rem = t & (HW_ - 1); int j = rem & 511;
  const float* row = hd + (t - j);
  float v = 0.0f;
  for (int d = 0; d < 25; d++) {
    int jj = j - 12 + d;
    if (jj >= 0 && jj < 512) v += g[d] * row[jj];
  }
  out[t] = v;
}

// sum of vertical-conv outputs via boundary weights: sumS[b]=Σs, Z[b]=Σsd
__global__ void k_sums(const float* __restrict__ b1, const float* __restrict__ b2,
                       float* sumS, float* Zb) {
  __shared__ float g[26];
  make_g25(g);
  int img = blockIdx.x >> 6, blk = blockIdx.x & 63;
  size_t o = (size_t)img * HW_ + blk * 4096;
  float s1 = 0.0f, s2 = 0.0f;
  for (int i = threadIdx.x; i < 4096; i += 256) {
    size_t idx = o + i;
    int rem = (int)(idx & (HW_ - 1)); int y = rem >> 9;
    int k0 = y - 499; if (k0 < 0) k0 = 0;
    int k1 = y + 12; if (k1 > 24) k1 = 24;
    float wv = 0.0f;
    for (int k = k0; k <= k1; k++) wv += g[k];
    s1 += b1[idx] * wv; s2 += b2[idx] * wv;
  }
  __shared__ float red[256];
  float t1 = brsum<256>(s1, red);
  float t2 = brsum<256>(s2, red);
  if (threadIdx.x == 0) { atomicAdd(&sumS[img], t1); atomicAdd(&Zb[img], t2); }
}

// fused vertical convs + KL reduction
__global__ void k_match(const float* __restrict__ b1, const float* __restrict__ b2,
                        const float* sumS, const float* Zb, float* macc) {
  __shared__ float g[26];
  make_g25(g);
  int img = blockIdx.x >> 6, blk = blockIdx.x & 63;
  size_t base = (size_t)img * HW_ + (size_t)blk * 4096;
  float Z = Zb[img];
  float logS = logf(sumS[img] + (float)HW_ * 1e-8f);
  float acc = 0.0f;
  for (int e = threadIdx.x; e < 4096; e += 256) {
    size_t idx = base + e;
    int rem = (int)(idx & (HW_ - 1)); int i = rem >> 9; int j = rem & 511;
    float s = 0.0f, sd = 0.0f;
    size_t colbase = (size_t)img * HW_ + j;
    for (int k = 0; k < 25; k++) {
      int y = i + k - 12;
      if (y >= 0 && y < 512) {
        size_t ro = colbase + (size_t)y * 512;
        s += g[k] * b1[ro];
        sd += g[k] * b2[ro];
      }
    }
    float p = sd / Z;
    if (p > 0.0f)
      acc += p * (logf(fmaxf(p, 1e-30f)) - (logf(s + 1e-8f) - logS));
  }
  __shared__ float red[256];
  float tot = brsum<256>(acc, red);
  if (threadIdx.x == 0) atomicAdd(macc, tot);
}

// ---------- keypoint sampling ----------
__global__ void k_h51(const float* __restrict__ kp, float* out) {
  __shared__ float wc[51];
  make_w51(wc);
  int t = blockIdx.x * 256 + threadIdx.x;
  int rem = t & (HW_ - 1); int j = rem & 511;
  const float* row = kp + (t - j);
  float v = 0.0f;
  for (int d = 0; d < 51; d++) {
    int jj = j - 25 + d;
    if (jj >= 0 && jj < 512) v += wc[d] * ((row[jj] + 1e-6f) * 1e4f);
  }
  out[t] = v;
}

__global__ void k_smw(const float* __restrict__ kp, const float* __restrict__ b1, float* out) {
  __shared__ float wc[51];
  make_w51(wc);
  int t = blockIdx.x * 256 + threadIdx.x;
  int rem = t & (HW_ - 1); int i = rem >> 9; int j = rem & 511;
  int img = t >> 18;
  size_t colbase = (size_t)img * HW_ + j;
  float v = 0.0f;
  for (int k = 0; k < 51; k++) {
    int y = i + k - 25;
    if (y >= 0 && y < 512) v += wc[k] * b1[colbase + (size_t)y * 512];
  }
  out[t] = kp[t] / sqrtf(v + 1e-8f);
}

__global__ void k_nms(const float* __restrict__ in, float* out) {
  int t = blockIdx.x * 256 + threadIdx.x;
  int rem = t & (HW_ - 1); int i = rem >> 9; int j = rem & 511;
  int img = t >> 18;
  float v = in[t];
  float mx = -3.4e38f;
  for (int dy = -2; dy <= 2; dy++) {
    int y = i + dy; if (y < 0 || y >= 512) continue;
    size_t ro = (size_t)img * HW_ + (size_t)y * 512;
    for (int dx = -2; dx <= 2; dx++) {
      int x = j + dx; if (x < 0 || x >= 512) continue;
      mx = fmaxf(mx, in[ro + x]);
    }
  }
  out[t] = (v == mx) ? v : 0.0f;
}

__global__ void k_hist(const float* __restrict__ in, unsigned* hist) {
  int t = blockIdx.x * 256 + threadIdx.x;
  int img = t >> 18;
  float v = in[t];
  if (v != 0.0f)
    atomicAdd(&hist[(size_t)img * 65536 + (__float_as_uint(v) >> 16)], 1u);
}

__global__ void k_thresh(const unsigned* __restrict__ hist, unsigned* Tb, unsigned* needb) {
  int img = blockIdx.x;
  const unsigned* h = hist + (size_t)img * 65536;
  __shared__ unsigned part[256];
  __shared__ unsigned scan[257];
  int t = threadIdx.x;
  unsigned s = 0;
  for (int k = 0; k < 256; k++) {
    int bin = 65535 - (t * 256 + k);
    s += (bin == 0) ? 0x00100000u : h[bin];
  }
  part[t] = s; __syncthreads();
  if (t == 0) {
    unsigned c = 0;
    for (int k = 0; k < 256; k++) { scan[k] = c; c += part[k]; }
    scan[256] = c;
  }
  __syncthreads();
  unsigned pre = scan[t];
  if (pre < MK && pre + part[t] >= MK) {
    unsigned c = pre;
    for (int k = 0; k < 256; k++) {
      int bin = 65535 - (t * 256 + k);
      unsigned cnt = (bin == 0) ? 0x00100000u : h[bin];
      if (c + cnt >= MK) { Tb[img] = (unsigned)bin; needb[img] = MK - c; break; }
      c += cnt;
    }
  }
}

__global__ void k_collect(const float* __restrict__ in, const unsigned* Tb,
                          unsigned* selcnt, unsigned* sel,
                          unsigned* bcnt, unsigned long long* bnd) {
  int t = blockIdx.x * 256 + threadIdx.x;
  int img = t >> 18;
  unsigned idx = (unsigned)(t & (HW_ - 1));
  float v = in[t];
  unsigned bits = __float_as_uint(v);
  unsigned bin = bits >> 16;
  unsigned T = Tb[img];
  if (bin > T) {
    unsigned p = atomicAdd(&selcnt[img], 1u);
    if (p < MK) sel[img * MK + p] = idx;
  } else if (bin == T) {
    unsigned p = atomicAdd(&bcnt[img], 1u);
    if (p < CAPB)
      bnd[(size_t)img * CAPB + p] =
          ((unsigned long long)bits << 32) | (unsigned long long)(idx ^ 0xFFFFFFFFu);
  }
}

__global__ void __launch_bounds__(1024)
k_finsel(const unsigned long long* __restrict__ bnd, const unsigned* bcnt,
         const unsigned* needb, const unsigned* selcnt, unsigned* sel) {
  int img = blockIdx.x;
  __shared__ unsigned long long key[CAPB];
  unsigned bn = bcnt[img];
  int n = (bn < CAPB) ? (int)bn : CAPB;
  int t = threadIdx.x;
  for (int k = t; k < CAPB; k += 1024)
    key[k] = (k < n) ? bnd[(size_t)img * CAPB + k] : 0ull;
  __syncthreads();
  // bitonic sort, descending (value desc, then idx asc via ~idx in low bits)
  for (int sz = 2; sz <= CAPB; sz <<= 1) {
    for (int st = sz >> 1; st > 0; st >>= 1) {
      for (int i = t; i < CAPB; i += 1024) {
        int l = i ^ st;
        if (l > i) {
          unsigned long long a = key[i], b = key[l];
          bool up = ((i & sz) == 0);
          if (up ? (a < b) : (a > b)) { key[i] = b; key[l] = a; }
        }
      }
      __syncthreads();
    }
  }
  unsigned c1 = selcnt[img]; if (c1 > MK) c1 = MK;
  unsigned need = needb[img];
  unsigned kk = need; if (kk > MK - c1) kk = MK - c1;
  for (unsigned m = t; m < MK - c1; m += 1024) {
    unsigned v = 0u;
    if (m < kk && m < (unsigned)n)
      v = (unsigned)(key[m] & 0xFFFFFFFFull) ^ 0xFFFFFFFFu;
    sel[img * MK + c1 + m] = v;
  }
}

// ---------- sparse loss ----------
__global__ void k_prep(const unsigned* __restrict__ sel, const float* __restrict__ scoremap,
                       const float* __restrict__ gtA, const float* __restrict__ gtB,
                       const float* __restrict__ vA, const float* __restrict__ vB,
                       float* px, float* py, float* wx, float* wy, float* lg, float* sl) {
  int t = blockIdx.x * 256 + threadIdx.x;  // 0..32767
  int img = t >> 11;
  unsigned idx = sel[t] & (HW_ - 1);
  int h = idx >> 9, w = idx & 511;
  px[t] = (w + 0.5f) * (2.0f / 512.0f) - 1.0f;
  py[t] = (h + 0.5f) * (2.0f / 512.0f) - 1.0f;
  int b = (img < 8) ? img : img - 8;
  const float* gt = (img < 8) ? gtA : gtB;
  const float* vv = (img < 8) ? vA : vB;
  size_t pix = (size_t)b * HW_ + idx;
  wx[t] = gt[pix * 4 + 2];
  wy[t] = gt[pix * 4 + 3];
  lg[t] = (vv[pix] > 0.0f) ? 1.0f : 0.0f;
  sl[t] = scoremap[(size_t)img * HW_ + idx];
}

__global__ void k_mindist(const float* __restrict__ px, const float* __restrict__ py,
                          const float* __restrict__ wx, const float* __restrict__ wy,
                          float* r) {
  __shared__ float ox[MK], oy[MK];
  int img = blockIdx.x >> 3, ch = blockIdx.x & 7;
  int opp = (img < 8) ? img + 8 : img - 8;
  for (int k = threadIdx.x; k < MK; k += 256) {
    ox[k] = px[opp * MK + k];
    oy[k] = py[opp * MK + k];
  }
  __syncthreads();
  int m = img * MK + ch * 256 + threadIdx.x;
  float ax = wx[m], ay = wy[m];
  float d2 = 3.4e38f;
  for (int n = 0; n < MK; n++) {
    float dx = ax - ox[n], dy = ay - oy[n];
    d2 = fminf(d2, dx * dx + dy * dy);
  }
  r[m] = expf(-100.0f * sqrtf(d2 + 1e-12f));
}

__global__ void __launch_bounds__(1024)
k_loss(const float* __restrict__ sl, const float* __restrict__ lg,
       const float* __restrict__ r, float* sacc) {
  int img = blockIdx.x;
  __shared__ float red[1024];
  int t = threadIdx.x;
  int i0 = img * MK + t, i1 = i0 + 1024;
  float s0 = sl[i0], s1 = sl[i1];
  float g0 = lg[i0], g1 = lg[i1];
  float l0 = (g0 > 0.0f) ? s0 : -1e9f;
  float l1 = (g1 > 0.0f) ? s1 : -1e9f;
  float mx = brmax<1024>(fmaxf(l0, l1), red);
  float se = brsum<1024>(expf(l0 - mx) + expf(l1 - mx), red);
  float lse = mx + logf(se);
  float a = 0.0f;
  if (g0 > 0.0f) a += r[i0] * (s0 - lse);
  if (g1 > 0.0f) a += r[i1] * (s1 - lse);
  float tot = brsum<1024>(a, red);
  if (t == 0) atomicAdd(sacc, -tot);
}

__global__ void k_out(const float* macc, const float* sacc, float* out) {
  out[0] = sacc[0] + macc[0] * (1.0f / 16.0f);
}

// ---------- launch ----------
extern "C" void kernel_launch(void* const* d_in, const int* in_sizes, int n_in,
                              void* d_out, int out_size, void* d_ws, size_t ws_size,
                              hipStream_t stream) {
  const float* scoremap = (const float*)d_in[0];
  const float* gtA = (const float*)d_in[1];
  const float* gtB = (const float*)d_in[2];
  const float* vA  = (const float*)d_in[3];
  const float* vB  = (const float*)d_in[4];
  const float* hd  = (const float*)d_in[5];

  char* ws = (char*)d_ws;
  float* A  = (float*)(ws);
  float* B1 = (float*)(ws + OFF_B1);
  float* B2 = (float*)(ws + OFF_B2);

  char* sm = ws + OFF_SMALL;
  unsigned* mxb    = (unsigned*)(sm + 0);
  float*    sume   = (float*)(sm + 64);
  float*    sumS   = (float*)(sm + 128);
  float*    Zb     = (float*)(sm + 192);
  unsigned* Tb     = (unsigned*)(sm + 256);
  unsigned* needb  = (unsigned*)(sm + 320);
  unsigned* selcnt = (unsigned*)(sm + 384);
  unsigned* bcnt   = (unsigned*)(sm + 448);
  float*    macc   = (float*)(sm + 512);
  float*    sacc   = (float*)(sm + 516);

  unsigned* hist = (unsigned*)(ws + OFF_HIST);
  unsigned* sel  = (unsigned*)(ws + OFF_SEL);
  unsigned long long* bnd = (unsigned long long*)(ws + OFF_BND);
  float* px = (float*)(ws + OFF_PX);
  float* py = (float*)(ws + OFF_PY);
  float* wx = (float*)(ws + OFF_WXp);
  float* wy = (float*)(ws + OFF_WYp);
  float* lg = (float*)(ws + OFF_LG);
  float* sl = (float*)(ws + OFF_SL);
  float* rr = (float*)(ws + OFF_R);

  float* out = (float*)d_out;

  hipMemsetAsync(sm, 0, 1024, stream);

  // softmax -> kp_p in A
  k_max<<<1024, 256, 0, stream>>>(scoremap, mxb);
  k_expsum<<<1024, 256, 0, stream>>>(scoremap, A, mxb, sume);
  k_norm<<<16384, 256, 0, stream>>>(A, sume);

  // matchability
  k_hvalid<<<16384, 256, 0, stream>>>(A, B1);
  k_hstd<<<16384, 256, 0, stream>>>(hd, B2);
  k_sums<<<1024, 256, 0, stream>>>(B1, B2, sumS, Zb);
  k_match<<<1024, 256, 0, stream>>>(B1, B2, sumS, Zb, macc);

  // coverage-reweighted scoremap
  k_h51<<<16384, 256, 0, stream>>>(A, B1);
  k_smw<<<16384, 256, 0, stream>>>(A, B1, B2);

  // A is now free: zero histogram region
  hipMemsetAsync(ws + OFF_HIST, 0, (size_t)16 * 65536 * 4, stream);

  // NMS + top-k selection
  k_nms<<<16384, 256, 0, stream>>>(B2, B1);
  k_hist<<<16384, 256, 0, stream>>>(B1, hist);
  k_thresh<<<16, 256, 0, stream>>>(hist, Tb, needb);
  k_collect<<<16384, 256, 0, stream>>>(B1, Tb, selcnt, sel, bcnt, bnd);
  k_finsel<<<16, 1024, 0, stream>>>(bnd, bcnt, needb, selcnt, sel);

  // sparse loss
  k_prep<<<128, 256, 0, stream>>>(sel, scoremap, gtA, gtB, vA, vB, px, py, wx, wy, lg, sl);
  k_mindist<<<128, 256, 0, stream>>>(px, py, wx, wy, rr);
  k_loss<<<16, 1024, 0, stream>>>(sl, lg, rr, sacc);

  k_out<<<1, 1, 0, stream>>>(macc, sacc, out);
}

// Round 2
// 862.501 us; speedup vs baseline: 1.4100x; 1.4100x over previous
//
#include <hip/hip_runtime.h>

#define HH 512
#define WW 512
#define HW_ 262144
#define NIMG 16
#define MK 2048
#define CAPB 4096

static constexpr size_t OFF_B1    = 16777216;   // 16MB
static constexpr size_t OFF_B2    = 33554432;   // 32MB
static constexpr size_t OFF_SMALL = 50331648;   // 48MB
// regions inside buffer A (free after smw is computed):
static constexpr size_t OFF_HIST = 0;           // 16*65536*4 = 4MB
static constexpr size_t OFF_SEL  = 4194304;     // 16*2048*4
static constexpr size_t OFF_BND  = 4325376;     // 16*4096*8
static constexpr size_t OFF_PX   = 4849664;
static constexpr size_t OFF_PY   = 4980736;
static constexpr size_t OFF_WXp  = 5111808;
static constexpr size_t OFF_WYp  = 5242880;
static constexpr size_t OFF_LG   = 5373952;
static constexpr size_t OFF_SL   = 5505024;
static constexpr size_t OFF_R    = 5636096;

// per-image counters padded to 128B (32 u32) to kill cacheline serialization
#define CSTRIDE 32

// ---------- helpers ----------
template<int B>
__device__ __forceinline__ float brsum(float v, float* red) {
  int t = threadIdx.x;
  red[t] = v; __syncthreads();
  for (int s = B >> 1; s > 0; s >>= 1) {
    if (t < s) red[t] += red[t + s];
    __syncthreads();
  }
  float r = red[0]; __syncthreads();
  return r;
}
template<int B>
__device__ __forceinline__ float brmax(float v, float* red) {
  int t = threadIdx.x;
  red[t] = v; __syncthreads();
  for (int s = B >> 1; s > 0; s >>= 1) {
    if (t < s) red[t] = fmaxf(red[t], red[t + s]);
    __syncthreads();
  }
  float r = red[0]; __syncthreads();
  return r;
}

// gaussian (25 taps, normalized), slot 25 = scratch sum
__device__ __forceinline__ void make_g25(float* g) {
  int t = threadIdx.x;
  if (t < 25) {
    float x = -1.0f + (float)t * (2.0f / 24.0f);
    g[t] = expf(-(x * x) / 0.5f);
  }
  __syncthreads();
  if (t == 0) {
    float s = 0.0f;
    for (int k = 0; k < 25; k++) s += g[k];
    g[25] = s;
  }
  __syncthreads();
  if (t < 25) g[t] = g[t] / g[25];
  __syncthreads();
}
// coverage weights (51 taps, unnormalized)
__device__ __forceinline__ void make_w51(float* wc) {
  int t = threadIdx.x;
  if (t < 51) {
    float x = -2.0f + (float)t * (4.0f / 50.0f);
    wc[t] = expf(-x * x);
  }
  __syncthreads();
}

// ---------- softmax (no max-subtraction: inputs are O(1), exp is safe) ----------
__global__ void k_expsum(const float* __restrict__ x, float* kp, float* sume) {
  int img = blockIdx.x >> 6, blk = blockIdx.x & 63;
  size_t o = (size_t)img * HW_ + blk * 4096;
  float s = 0.0f;
  for (int i = threadIdx.x; i < 4096; i += 256) {
    float e = expf(x[o + i]);
    kp[o + i] = e; s += e;
  }
  __shared__ float red[256];
  s = brsum<256>(s, red);
  if (threadIdx.x == 0) atomicAdd(&sume[img * CSTRIDE], s);
}

// ---------- matchability: merged horizontal convs ----------
// b1 = valid-conv(kp_p) (asymmetric-pad bug: cols [12,499] else 0), normalized
// b2 = zero-padded conv(has_depth)
__global__ void k_hconv(const float* __restrict__ A, const float* __restrict__ hd,
                        const float* __restrict__ sume, float* b1, float* b2) {
  __shared__ float g[26];
  make_g25(g);
  int t = blockIdx.x * 256 + threadIdx.x;
  int rem = t & (HW_ - 1); int j = rem & 511;
  int img = t >> 18;
  float inv = 1.0f / sume[img * CSTRIDE];
  float v1 = 0.0f;
  if (j >= 12 && j <= 499) {
    const float* row = A + (t - j);
    for (int d = 0; d < 25; d++) v1 += g[d] * row[j - 12 + d];
  }
  b1[t] = v1 * inv;
  const float* row2 = hd + (t - j);
  float v2 = 0.0f;
  for (int d = 0; d < 25; d++) {
    int jj = j - 12 + d;
    if (jj >= 0 && jj < 512) v2 += g[d] * row2[jj];
  }
  b2[t] = v2;
}

// sum of vertical-conv outputs via boundary weights: sumS[b]=Σs, Z[b]=Σsd
__global__ void k_sums(const float* __restrict__ b1, const float* __restrict__ b2,
                       float* sumS, float* Zb) {
  __shared__ float g[26];
  make_g25(g);
  int img = blockIdx.x >> 6, blk = blockIdx.x & 63;
  size_t o = (size_t)img * HW_ + blk * 4096;
  float s1 = 0.0f, s2 = 0.0f;
  for (int i = threadIdx.x; i < 4096; i += 256) {
    size_t idx = o + i;
    int rem = (int)(idx & (HW_ - 1)); int y = rem >> 9;
    int k0 = y - 499; if (k0 < 0) k0 = 0;
    int k1 = y + 12; if (k1 > 24) k1 = 24;
    float wv = 0.0f;
    for (int k = k0; k <= k1; k++) wv += g[k];
    s1 += b1[idx] * wv; s2 += b2[idx] * wv;
  }
  __shared__ float red[256];
  float t1 = brsum<256>(s1, red);
  float t2 = brsum<256>(s2, red);
  if (threadIdx.x == 0) {
    atomicAdd(&sumS[img * CSTRIDE], t1);
    atomicAdd(&Zb[img * CSTRIDE], t2);
  }
}

// fused vertical convs + KL reduction
__global__ void k_match(const float* __restrict__ b1, const float* __restrict__ b2,
                        const float* sumS, const float* Zb, float* macc) {
  __shared__ float g[26];
  make_g25(g);
  int img = blockIdx.x >> 6, blk = blockIdx.x & 63;
  size_t base = (size_t)img * HW_ + (size_t)blk * 4096;
  float Z = Zb[img * CSTRIDE];
  float logS = logf(sumS[img * CSTRIDE] + (float)HW_ * 1e-8f);
  float acc = 0.0f;
  for (int e = threadIdx.x; e < 4096; e += 256) {
    size_t idx = base + e;
    int rem = (int)(idx & (HW_ - 1)); int i = rem >> 9; int j = rem & 511;
    float s = 0.0f, sd = 0.0f;
    size_t colbase = (size_t)img * HW_ + j;
    for (int k = 0; k < 25; k++) {
      int y = i + k - 12;
      if (y >= 0 && y < 512) {
        size_t ro = colbase + (size_t)y * 512;
        s += g[k] * b1[ro];
        sd += g[k] * b2[ro];
      }
    }
    float p = sd / Z;
    if (p > 0.0f)
      acc += p * (logf(fmaxf(p, 1e-30f)) - (logf(s + 1e-8f) - logS));
  }
  __shared__ float red[256];
  float tot = brsum<256>(acc, red);
  if (threadIdx.x == 0) atomicAdd(macc, tot);
}

// ---------- keypoint sampling ----------
// horizontal 51-tap on (kp + 1e-6)*1e4 with normalization folded in:
// tap = a*(1e4/sume) + 1e-2
__global__ void k_h51(const float* __restrict__ A, const float* __restrict__ sume,
                      float* out) {
  __shared__ float wc[51];
  make_w51(wc);
  int t = blockIdx.x * 256 + threadIdx.x;
  int rem = t & (HW_ - 1); int j = rem & 511;
  int img = t >> 18;
  float s1 = 1e4f / sume[img * CSTRIDE];
  const float* row = A + (t - j);
  float v = 0.0f;
  for (int d = 0; d < 51; d++) {
    int jj = j - 25 + d;
    if (jj >= 0 && jj < 512) v = fmaf(wc[d], fmaf(row[jj], s1, 1e-2f), v);
  }
  out[t] = v;
}

__global__ void k_smw(const float* __restrict__ A, const float* __restrict__ sume,
                      const float* __restrict__ b1, float* out) {
  __shared__ float wc[51];
  make_w51(wc);
  int t = blockIdx.x * 256 + threadIdx.x;
  int rem = t & (HW_ - 1); int i = rem >> 9; int j = rem & 511;
  int img = t >> 18;
  float inv = 1.0f / sume[img * CSTRIDE];
  size_t colbase = (size_t)img * HW_ + j;
  float v = 0.0f;
  for (int k = 0; k < 51; k++) {
    int y = i + k - 25;
    if (y >= 0 && y < 512) v += wc[k] * b1[colbase + (size_t)y * 512];
  }
  out[t] = (A[t] * inv) / sqrtf(v + 1e-8f);
}

// NMS + fused histogram of survivors
__global__ void k_nms(const float* __restrict__ in, float* out, unsigned* hist) {
  int t = blockIdx.x * 256 + threadIdx.x;
  int rem = t & (HW_ - 1); int i = rem >> 9; int j = rem & 511;
  int img = t >> 18;
  float v = in[t];
  float mx = -3.4e38f;
  for (int dy = -2; dy <= 2; dy++) {
    int y = i + dy; if (y < 0 || y >= 512) continue;
    size_t ro = (size_t)img * HW_ + (size_t)y * 512;
    for (int dx = -2; dx <= 2; dx++) {
      int x = j + dx; if (x < 0 || x >= 512) continue;
      mx = fmaxf(mx, in[ro + x]);
    }
  }
  float r = (v == mx) ? v : 0.0f;
  out[t] = r;
  if (r != 0.0f)
    atomicAdd(&hist[(size_t)img * 65536 + (__float_as_uint(r) >> 16)], 1u);
}

__global__ void k_thresh(const unsigned* __restrict__ hist, unsigned* Tb, unsigned* needb) {
  int img = blockIdx.x;
  const unsigned* h = hist + (size_t)img * 65536;
  __shared__ unsigned part[256];
  __shared__ unsigned scan[257];
  int t = threadIdx.x;
  unsigned s = 0;
  for (int k = 0; k < 256; k++) {
    int bin = 65535 - (t * 256 + k);
    s += (bin == 0) ? 0x00100000u : h[bin];
  }
  part[t] = s; __syncthreads();
  if (t == 0) {
    unsigned c = 0;
    for (int k = 0; k < 256; k++) { scan[k] = c; c += part[k]; }
    scan[256] = c;
  }
  __syncthreads();
  unsigned pre = scan[t];
  if (pre < MK && pre + part[t] >= MK) {
    unsigned c = pre;
    for (int k = 0; k < 256; k++) {
      int bin = 65535 - (t * 256 + k);
      unsigned cnt = (bin == 0) ? 0x00100000u : h[bin];
      if (c + cnt >= MK) { Tb[img * CSTRIDE] = (unsigned)bin; needb[img * CSTRIDE] = MK - c; break; }
      c += cnt;
    }
  }
}

// wave-aggregated compaction: 1 atomic per wave per stream, per-image padded counters
__global__ void k_collect(const float* __restrict__ in, const unsigned* __restrict__ Tb,
                          unsigned* selcnt, unsigned* sel,
                          unsigned* bcnt, unsigned long long* bnd) {
  int t = blockIdx.x * 256 + threadIdx.x;
  int img = t >> 18;
  unsigned idx = (unsigned)(t & (HW_ - 1));
  float v = in[t];
  unsigned bits = __float_as_uint(v);
  unsigned bin = bits >> 16;
  unsigned T = Tb[img * CSTRIDE];
  bool c1 = bin > T;
  bool c2 = bin == T;
  int lane = threadIdx.x & 63;
  unsigned long long lowmask = (1ull << lane) - 1ull;

  unsigned long long m1 = __ballot(c1);
  if (m1) {
    int leader = __ffsll(m1) - 1;
    unsigned base = 0;
    if (lane == leader) base = atomicAdd(&selcnt[img * CSTRIDE], (unsigned)__popcll(m1));
    base = __shfl(base, leader);
    if (c1) {
      unsigned p = base + (unsigned)__popcll(m1 & lowmask);
      if (p < MK) sel[img * MK + p] = idx;
    }
  }
  unsigned long long m2 = __ballot(c2);
  if (m2) {
    int leader = __ffsll(m2) - 1;
    unsigned base = 0;
    if (lane == leader) base = atomicAdd(&bcnt[img * CSTRIDE], (unsigned)__popcll(m2));
    base = __shfl(base, leader);
    if (c2) {
      unsigned p = base + (unsigned)__popcll(m2 & lowmask);
      if (p < CAPB)
        bnd[(size_t)img * CAPB + p] =
            ((unsigned long long)bits << 32) | (unsigned long long)(idx ^ 0xFFFFFFFFu);
    }
  }
}

__global__ void __launch_bounds__(1024)
k_finsel(const unsigned long long* __restrict__ bnd, const unsigned* bcnt,
         const unsigned* needb, const unsigned* selcnt, unsigned* sel) {
  int img = blockIdx.x;
  __shared__ unsigned long long key[CAPB];
  unsigned bn = bcnt[img * CSTRIDE];
  int n = (bn < CAPB) ? (int)bn : CAPB;
  int t = threadIdx.x;
  for (int k = t; k < CAPB; k += 1024)
    key[k] = (k < n) ? bnd[(size_t)img * CAPB + k] : 0ull;
  __syncthreads();
  // bitonic sort, descending (value desc, then idx asc via ~idx in low bits)
  for (int sz = 2; sz <= CAPB; sz <<= 1) {
    for (int st = sz >> 1; st > 0; st >>= 1) {
      for (int i = t; i < CAPB; i += 1024) {
        int l = i ^ st;
        if (l > i) {
          unsigned long long a = key[i], b = key[l];
          bool up = ((i & sz) == 0);
          if (up ? (a < b) : (a > b)) { key[i] = b; key[l] = a; }
        }
      }
      __syncthreads();
    }
  }
  unsigned c1 = selcnt[img * CSTRIDE]; if (c1 > MK) c1 = MK;
  unsigned need = needb[img * CSTRIDE];
  unsigned kk = need; if (kk > MK - c1) kk = MK - c1;
  for (unsigned m = t; m < MK - c1; m += 1024) {
    unsigned v = 0u;
    if (m < kk && m < (unsigned)n)
      v = (unsigned)(key[m] & 0xFFFFFFFFull) ^ 0xFFFFFFFFu;
    sel[img * MK + c1 + m] = v;
  }
}

// ---------- sparse loss ----------
__global__ void k_prep(const unsigned* __restrict__ sel, const float* __restrict__ scoremap,
                       const float* __restrict__ gtA, const float* __restrict__ gtB,
                       const float* __restrict__ vA, const float* __restrict__ vB,
                       float* px, float* py, float* wx, float* wy, float* lg, float* sl) {
  int t = blockIdx.x * 256 + threadIdx.x;  // 0..32767
  int img = t >> 11;
  unsigned idx = sel[t] & (HW_ - 1);
  int h = idx >> 9, w = idx & 511;
  px[t] = (w + 0.5f) * (2.0f / 512.0f) - 1.0f;
  py[t] = (h + 0.5f) * (2.0f / 512.0f) - 1.0f;
  int b = (img < 8) ? img : img - 8;
  const float* gt = (img < 8) ? gtA : gtB;
  const float* vv = (img < 8) ? vA : vB;
  size_t pix = (size_t)b * HW_ + idx;
  wx[t] = gt[pix * 4 + 2];
  wy[t] = gt[pix * 4 + 3];
  lg[t] = (vv[pix] > 0.0f) ? 1.0f : 0.0f;
  sl[t] = scoremap[(size_t)img * HW_ + idx];
}

__global__ void k_mindist(const float* __restrict__ px, const float* __restrict__ py,
                          const float* __restrict__ wx, const float* __restrict__ wy,
                          float* r) {
  __shared__ float ox[MK], oy[MK];
  int img = blockIdx.x >> 3, ch = blockIdx.x & 7;
  int opp = (img < 8) ? img + 8 : img - 8;
  for (int k = threadIdx.x; k < MK; k += 256) {
    ox[k] = px[opp * MK + k];
    oy[k] = py[opp * MK + k];
  }
  __syncthreads();
  int m = img * MK + ch * 256 + threadIdx.x;
  float ax = wx[m], ay = wy[m];
  float d2 = 3.4e38f;
  for (int n = 0; n < MK; n++) {
    float dx = ax - ox[n], dy = ay - oy[n];
    d2 = fminf(d2, dx * dx + dy * dy);
  }
  r[m] = expf(-100.0f * sqrtf(d2 + 1e-12f));
}

__global__ void __launch_bounds__(1024)
k_loss(const float* __restrict__ sl, const float* __restrict__ lg,
       const float* __restrict__ r, float* sacc) {
  int img = blockIdx.x;
  __shared__ float red[1024];
  int t = threadIdx.x;
  int i0 = img * MK + t, i1 = i0 + 1024;
  float s0 = sl[i0], s1 = sl[i1];
  float g0 = lg[i0], g1 = lg[i1];
  float l0 = (g0 > 0.0f) ? s0 : -1e9f;
  float l1 = (g1 > 0.0f) ? s1 : -1e9f;
  float mx = brmax<1024>(fmaxf(l0, l1), red);
  float se = brsum<1024>(expf(l0 - mx) + expf(l1 - mx), red);
  float lse = mx + logf(se);
  float a = 0.0f;
  if (g0 > 0.0f) a += r[i0] * (s0 - lse);
  if (g1 > 0.0f) a += r[i1] * (s1 - lse);
  float tot = brsum<1024>(a, red);
  if (t == 0) atomicAdd(sacc, -tot);
}

__global__ void k_out(const float* macc, const float* sacc, float* out) {
  out[0] = sacc[0] + macc[0] * (1.0f / 16.0f);
}

// ---------- launch ----------
extern "C" void kernel_launch(void* const* d_in, const int* in_sizes, int n_in,
                              void* d_out, int out_size, void* d_ws, size_t ws_size,
                              hipStream_t stream) {
  const float* scoremap = (const float*)d_in[0];
  const float* gtA = (const float*)d_in[1];
  const float* gtB = (const float*)d_in[2];
  const float* vA  = (const float*)d_in[3];
  const float* vB  = (const float*)d_in[4];
  const float* hd  = (const float*)d_in[5];

  char* ws = (char*)d_ws;
  float* A  = (float*)(ws);
  float* B1 = (float*)(ws + OFF_B1);
  float* B2 = (float*)(ws + OFF_B2);

  char* sm = ws + OFF_SMALL;
  float*    sume   = (float*)(sm + 0);      // 16 imgs * 128B
  float*    sumS   = (float*)(sm + 2048);
  float*    Zb     = (float*)(sm + 4096);
  unsigned* Tb     = (unsigned*)(sm + 6144);
  unsigned* needb  = (unsigned*)(sm + 8192);
  unsigned* selcnt = (unsigned*)(sm + 10240);
  unsigned* bcnt   = (unsigned*)(sm + 12288);
  float*    macc   = (float*)(sm + 14336);
  float*    sacc   = (float*)(sm + 14464);

  unsigned* hist = (unsigned*)(ws + OFF_HIST);
  unsigned* sel  = (unsigned*)(ws + OFF_SEL);
  unsigned long long* bnd = (unsigned long long*)(ws + OFF_BND);
  float* px = (float*)(ws + OFF_PX);
  float* py = (float*)(ws + OFF_PY);
  float* wx = (float*)(ws + OFF_WXp);
  float* wy = (float*)(ws + OFF_WYp);
  float* lg = (float*)(ws + OFF_LG);
  float* sl = (float*)(ws + OFF_SL);
  float* rr = (float*)(ws + OFF_R);

  float* out = (float*)d_out;

  hipMemsetAsync(sm, 0, 16384, stream);

  // softmax (unnormalized exp in A; sume holds per-image Σexp)
  k_expsum<<<1024, 256, 0, stream>>>(scoremap, A, sume);

  // matchability
  k_hconv<<<16384, 256, 0, stream>>>(A, hd, sume, B1, B2);
  k_sums<<<1024, 256, 0, stream>>>(B1, B2, sumS, Zb);
  k_match<<<1024, 256, 0, stream>>>(B1, B2, sumS, Zb, macc);

  // coverage-reweighted scoremap
  k_h51<<<16384, 256, 0, stream>>>(A, sume, B1);
  k_smw<<<16384, 256, 0, stream>>>(A, sume, B1, B2);

  // A is now free: zero histogram region (must be before k_nms which fills it)
  hipMemsetAsync(ws + OFF_HIST, 0, (size_t)16 * 65536 * 4, stream);

  // NMS (+fused hist) + top-k selection
  k_nms<<<16384, 256, 0, stream>>>(B2, B1, hist);
  k_thresh<<<16, 256, 0, stream>>>(hist, Tb, needb);
  k_collect<<<16384, 256, 0, stream>>>(B1, Tb, selcnt, sel, bcnt, bnd);
  k_finsel<<<16, 1024, 0, stream>>>(bnd, bcnt, needb, selcnt, sel);

  // sparse loss
  k_prep<<<128, 256, 0, stream>>>(sel, scoremap, gtA, gtB, vA, vB, px, py, wx, wy, lg, sl);
  k_mindist<<<128, 256, 0, stream>>>(px, py, wx, wy, rr);
  k_loss<<<16, 1024, 0, stream>>>(sl, lg, rr, sacc);

  k_out<<<1, 1, 0, stream>>>(macc, sacc, out);
}

// Round 3
// 611.870 us; speedup vs baseline: 1.9875x; 1.4096x over previous
//
#include <hip/hip_runtime.h>

#define HH 512
#define WW 512
#define HW_ 262144
#define NIMG 16
#define MK 2048
#define CAPB 4096

static constexpr size_t OFF_B1    = 16777216;   // 16MB
static constexpr size_t OFF_B2    = 33554432;   // 32MB
static constexpr size_t OFF_SMALL = 50331648;   // 48MB
// regions inside buffer A (free after smw is computed):
static constexpr size_t OFF_HIST = 0;           // 16*65536*4 = 4MB
static constexpr size_t OFF_SEL  = 4194304;     // 16*2048*4
static constexpr size_t OFF_BND  = 4325376;     // 16*4096*8
static constexpr size_t OFF_PX   = 4849664;
static constexpr size_t OFF_PY   = 4980736;
static constexpr size_t OFF_WXp  = 5111808;
static constexpr size_t OFF_WYp  = 5242880;
static constexpr size_t OFF_LG   = 5373952;
static constexpr size_t OFF_SL   = 5505024;
static constexpr size_t OFF_R    = 5636096;

// per-image counters padded to 128B (32 u32) to kill cacheline serialization
#define CSTRIDE 32

// ---------- helpers ----------
template<int B>
__device__ __forceinline__ float brsum(float v, float* red) {
  int t = threadIdx.x;
  red[t] = v; __syncthreads();
  for (int s = B >> 1; s > 0; s >>= 1) {
    if (t < s) red[t] += red[t + s];
    __syncthreads();
  }
  float r = red[0]; __syncthreads();
  return r;
}
template<int B>
__device__ __forceinline__ float brmax(float v, float* red) {
  int t = threadIdx.x;
  red[t] = v; __syncthreads();
  for (int s = B >> 1; s > 0; s >>= 1) {
    if (t < s) red[t] = fmaxf(red[t], red[t + s]);
    __syncthreads();
  }
  float r = red[0]; __syncthreads();
  return r;
}

// gaussian (25 taps, normalized), slot 25 = scratch sum
__device__ __forceinline__ void make_g25(float* g) {
  int t = threadIdx.x;
  if (t < 25) {
    float x = -1.0f + (float)t * (2.0f / 24.0f);
    g[t] = expf(-(x * x) / 0.5f);
  }
  __syncthreads();
  if (t == 0) {
    float s = 0.0f;
    for (int k = 0; k < 25; k++) s += g[k];
    g[25] = s;
  }
  __syncthreads();
  if (t < 25) g[t] = g[t] / g[25];
  __syncthreads();
}
// coverage weights (51 taps, unnormalized)
__device__ __forceinline__ void make_w51(float* wc) {
  int t = threadIdx.x;
  if (t < 51) {
    float x = -2.0f + (float)t * (4.0f / 50.0f);
    wc[t] = expf(-x * x);
  }
  __syncthreads();
}

// ---------- softmax (no max-subtraction: inputs are O(1), exp is safe) ----------
__global__ void k_expsum(const float* __restrict__ x, float* kp, float* sume) {
  int img = blockIdx.x >> 6, blk = blockIdx.x & 63;
  size_t o = (size_t)img * HW_ + blk * 4096;
  float s = 0.0f;
  for (int i = threadIdx.x; i < 4096; i += 256) {
    float e = expf(x[o + i]);
    kp[o + i] = e; s += e;
  }
  __shared__ float red[256];
  s = brsum<256>(s, red);
  if (threadIdx.x == 0) atomicAdd(&sume[img * CSTRIDE], s);
}

// ---------- matchability: merged horizontal convs + fused column-sum ----------
// b1 = valid-conv(kp_p) (asymmetric-pad bug: cols [12,499] else 0), normalized
// b2 = zero-padded conv(has_depth)
// also accumulates sumS = Σ vconv(b1), Zb = Σ vconv(b2) via boundary weights wv(y)
__global__ void __launch_bounds__(256)
k_hconv(const float* __restrict__ A, const float* __restrict__ hd,
        const float* __restrict__ sume, float* b1, float* b2,
        float* sumS, float* Zb) {
  __shared__ float g[26];
  __shared__ float ta[280];
  __shared__ float th[280];
  __shared__ float red[256];
  make_g25(g);
  int t0 = blockIdx.x * 256;
  int img = t0 >> 18;
  int rem = t0 & (HW_ - 1);
  int y = rem >> 9;
  int j0 = rem & 511;                 // 0 or 256 (block spans half a row)
  size_t rowbase = (size_t)(t0 - j0); // flat index of row start
  int tid = threadIdx.x;
  for (int i = tid; i < 280; i += 256) {
    int j = j0 - 12 + i;
    bool ok = (j >= 0 && j < 512);
    ta[i] = ok ? A[rowbase + j] : 0.0f;
    th[i] = ok ? hd[rowbase + j] : 0.0f;
  }
  __syncthreads();
  float inv = 1.0f / sume[img * CSTRIDE];
  int j = j0 + tid;
  float v1 = 0.0f;
  if (j >= 12 && j <= 499) {
    for (int d = 0; d < 25; d++) v1 = fmaf(g[d], ta[tid + d], v1);
  }
  v1 *= inv;
  float v2 = 0.0f;
  for (int d = 0; d < 25; d++) v2 = fmaf(g[d], th[tid + d], v2);
  b1[t0 + tid] = v1;
  b2[t0 + tid] = v2;
  // boundary weight for vertical conv column-sum (y constant per block)
  int k0 = y - 499; if (k0 < 0) k0 = 0;
  int k1 = y + 12;  if (k1 > 24) k1 = 24;
  float wv = 0.0f;
  for (int k = k0; k <= k1; k++) wv += g[k];
  float s1 = brsum<256>(v1, red);
  float s2 = brsum<256>(v2, red);
  if (tid == 0) {
    atomicAdd(&sumS[img * CSTRIDE], s1 * wv);
    atomicAdd(&Zb[img * CSTRIDE], s2 * wv);
  }
}

// fused vertical convs + KL reduction, LDS-tiled (64x64 out, 88x64 in, halo 12)
__global__ void __launch_bounds__(256)
k_match(const float* __restrict__ b1, const float* __restrict__ b2,
        const float* sumS, const float* Zb, float* macc) {
  __shared__ float g[26];
  __shared__ float t1[88 * 64];
  __shared__ float t2[88 * 64];
  __shared__ float red[256];
  make_g25(g);
  int blk = blockIdx.x;
  int img = blk >> 6;
  int ty = (blk >> 3) & 7;
  int tx = blk & 7;
  int y0 = ty * 64, x0 = tx * 64;
  const float* base1 = b1 + (size_t)img * HW_;
  const float* base2 = b2 + (size_t)img * HW_;
  for (int i = threadIdx.x; i < 88 * 64; i += 256) {
    int r = i >> 6, c = i & 63;
    int y = y0 + r - 12;
    float v1 = 0.0f, v2 = 0.0f;
    if (y >= 0 && y < 512) {
      size_t o = (size_t)y * 512 + x0 + c;
      v1 = base1[o]; v2 = base2[o];
    }
    t1[i] = v1; t2[i] = v2;
  }
  __syncthreads();
  float Z = Zb[img * CSTRIDE];
  float logS = logf(sumS[img * CSTRIDE] + (float)HW_ * 1e-8f);
  float acc = 0.0f;
  for (int k0 = 0; k0 < 16; k0++) {
    int i = threadIdx.x + k0 * 256;
    int r = i >> 6, c = i & 63;
    float s = 0.0f, sd = 0.0f;
    for (int k = 0; k < 25; k++) {
      s  = fmaf(g[k], t1[(r + k) * 64 + c], s);
      sd = fmaf(g[k], t2[(r + k) * 64 + c], sd);
    }
    float p = sd / Z;
    if (p > 0.0f)
      acc += p * (logf(fmaxf(p, 1e-30f)) - (logf(s + 1e-8f) - logS));
  }
  float tot = brsum<256>(acc, red);
  if (threadIdx.x == 0) atomicAdd(macc, tot);
}

// ---------- keypoint sampling ----------
// horizontal 51-tap on (kp + 1e-6)*1e4 with normalization folded in, LDS row tile
__global__ void __launch_bounds__(256)
k_h51(const float* __restrict__ A, const float* __restrict__ sume, float* out) {
  __shared__ float wc[51];
  __shared__ float ta[306];
  make_w51(wc);
  int t0 = blockIdx.x * 256;
  int img = t0 >> 18;
  int j0 = t0 & 511;
  size_t rowbase = (size_t)(t0 - j0);
  float s1 = 1e4f / sume[img * CSTRIDE];
  int tid = threadIdx.x;
  for (int i = tid; i < 306; i += 256) {
    int j = j0 - 25 + i;
    ta[i] = (j >= 0 && j < 512) ? fmaf(A[rowbase + j], s1, 1e-2f) : 0.0f;
  }
  __syncthreads();
  float v = 0.0f;
  for (int d = 0; d < 51; d++) v = fmaf(wc[d], ta[tid + d], v);
  out[t0 + tid] = v;
}

// vertical 51-tap + coverage reweight, LDS-tiled (64x64 out, 114x64 in, halo 25)
__global__ void __launch_bounds__(256)
k_smw(const float* __restrict__ A, const float* __restrict__ sume,
      const float* __restrict__ b1, float* out) {
  __shared__ float wc[51];
  __shared__ float t[114 * 64];
  make_w51(wc);
  int blk = blockIdx.x;
  int img = blk >> 6;
  int ty = (blk >> 3) & 7;
  int tx = blk & 7;
  int y0 = ty * 64, x0 = tx * 64;
  const float* base = b1 + (size_t)img * HW_;
  for (int i = threadIdx.x; i < 114 * 64; i += 256) {
    int r = i >> 6, c = i & 63;
    int y = y0 + r - 25;
    t[i] = (y >= 0 && y < 512) ? base[(size_t)y * 512 + x0 + c] : 0.0f;
  }
  __syncthreads();
  float inv = 1.0f / sume[img * CSTRIDE];
  for (int k0 = 0; k0 < 16; k0++) {
    int i = threadIdx.x + k0 * 256;
    int r = i >> 6, c = i & 63;
    float v = 0.0f;
    for (int k = 0; k < 51; k++) v = fmaf(wc[k], t[(r + k) * 64 + c], v);
    size_t o = (size_t)img * HW_ + (size_t)(y0 + r) * 512 + x0 + c;
    out[o] = (A[o] * inv) / sqrtf(v + 1e-8f);
  }
}

// NMS (5x5 max) LDS-tiled + fused histogram of survivors
__global__ void __launch_bounds__(256)
k_nms(const float* __restrict__ in, float* out, unsigned* hist) {
  __shared__ float t[68 * 68];
  int blk = blockIdx.x;
  int img = blk >> 6;
  int ty = (blk >> 3) & 7;
  int tx = blk & 7;
  int y0 = ty * 64, x0 = tx * 64;
  const float* base = in + (size_t)img * HW_;
  for (int i = threadIdx.x; i < 68 * 68; i += 256) {
    int r = i / 68, c = i - r * 68;
    int y = y0 + r - 2, x = x0 + c - 2;
    t[i] = (y >= 0 && y < 512 && x >= 0 && x < 512)
               ? base[(size_t)y * 512 + x] : -3.4e38f;
  }
  __syncthreads();
  for (int k0 = 0; k0 < 16; k0++) {
    int i = threadIdx.x + k0 * 256;
    int r = i >> 6, c = i & 63;
    float v = t[(r + 2) * 68 + (c + 2)];
    float mx = v;
    for (int dy = 0; dy < 5; dy++)
      for (int dx = 0; dx < 5; dx++)
        mx = fmaxf(mx, t[(r + dy) * 68 + (c + dx)]);
    float res = (v == mx) ? v : 0.0f;
    out[(size_t)img * HW_ + (size_t)(y0 + r) * 512 + x0 + c] = res;
    if (res != 0.0f)
      atomicAdd(&hist[(size_t)img * 65536 + (__float_as_uint(res) >> 16)], 1u);
  }
}

__global__ void k_thresh(const unsigned* __restrict__ hist, unsigned* Tb, unsigned* needb) {
  int img = blockIdx.x;
  const unsigned* h = hist + (size_t)img * 65536;
  __shared__ unsigned part[256];
  __shared__ unsigned scan[257];
  int t = threadIdx.x;
  unsigned s = 0;
  for (int k = 0; k < 256; k++) {
    int bin = 65535 - (t * 256 + k);
    s += (bin == 0) ? 0x00100000u : h[bin];
  }
  part[t] = s; __syncthreads();
  if (t == 0) {
    unsigned c = 0;
    for (int k = 0; k < 256; k++) { scan[k] = c; c += part[k]; }
    scan[256] = c;
  }
  __syncthreads();
  unsigned pre = scan[t];
  if (pre < MK && pre + part[t] >= MK) {
    unsigned c = pre;
    for (int k = 0; k < 256; k++) {
      int bin = 65535 - (t * 256 + k);
      unsigned cnt = (bin == 0) ? 0x00100000u : h[bin];
      if (c + cnt >= MK) { Tb[img * CSTRIDE] = (unsigned)bin; needb[img * CSTRIDE] = MK - c; break; }
      c += cnt;
    }
  }
}

// wave-aggregated compaction: 1 atomic per wave per stream, per-image padded counters
__global__ void k_collect(const float* __restrict__ in, const unsigned* __restrict__ Tb,
                          unsigned* selcnt, unsigned* sel,
                          unsigned* bcnt, unsigned long long* bnd) {
  int t = blockIdx.x * 256 + threadIdx.x;
  int img = t >> 18;
  unsigned idx = (unsigned)(t & (HW_ - 1));
  float v = in[t];
  unsigned bits = __float_as_uint(v);
  unsigned bin = bits >> 16;
  unsigned T = Tb[img * CSTRIDE];
  bool c1 = bin > T;
  bool c2 = bin == T;
  int lane = threadIdx.x & 63;
  unsigned long long lowmask = (1ull << lane) - 1ull;

  unsigned long long m1 = __ballot(c1);
  if (m1) {
    int leader = __ffsll(m1) - 1;
    unsigned base = 0;
    if (lane == leader) base = atomicAdd(&selcnt[img * CSTRIDE], (unsigned)__popcll(m1));
    base = __shfl(base, leader);
    if (c1) {
      unsigned p = base + (unsigned)__popcll(m1 & lowmask);
      if (p < MK) sel[img * MK + p] = idx;
    }
  }
  unsigned long long m2 = __ballot(c2);
  if (m2) {
    int leader = __ffsll(m2) - 1;
    unsigned base = 0;
    if (lane == leader) base = atomicAdd(&bcnt[img * CSTRIDE], (unsigned)__popcll(m2));
    base = __shfl(base, leader);
    if (c2) {
      unsigned p = base + (unsigned)__popcll(m2 & lowmask);
      if (p < CAPB)
        bnd[(size_t)img * CAPB + p] =
            ((unsigned long long)bits << 32) | (unsigned long long)(idx ^ 0xFFFFFFFFu);
    }
  }
}

__global__ void __launch_bounds__(1024)
k_finsel(const unsigned long long* __restrict__ bnd, const unsigned* bcnt,
         const unsigned* needb, const unsigned* selcnt, unsigned* sel) {
  int img = blockIdx.x;
  __shared__ unsigned long long key[CAPB];
  unsigned bn = bcnt[img * CSTRIDE];
  int n = (bn < CAPB) ? (int)bn : CAPB;
  int t = threadIdx.x;
  for (int k = t; k < CAPB; k += 1024)
    key[k] = (k < n) ? bnd[(size_t)img * CAPB + k] : 0ull;
  __syncthreads();
  // bitonic sort, descending (value desc, then idx asc via ~idx in low bits)
  for (int sz = 2; sz <= CAPB; sz <<= 1) {
    for (int st = sz >> 1; st > 0; st >>= 1) {
      for (int i = t; i < CAPB; i += 1024) {
        int l = i ^ st;
        if (l > i) {
          unsigned long long a = key[i], b = key[l];
          bool up = ((i & sz) == 0);
          if (up ? (a < b) : (a > b)) { key[i] = b; key[l] = a; }
        }
      }
      __syncthreads();
    }
  }
  unsigned c1 = selcnt[img * CSTRIDE]; if (c1 > MK) c1 = MK;
  unsigned need = needb[img * CSTRIDE];
  unsigned kk = need; if (kk > MK - c1) kk = MK - c1;
  for (unsigned m = t; m < MK - c1; m += 1024) {
    unsigned v = 0u;
    if (m < kk && m < (unsigned)n)
      v = (unsigned)(key[m] & 0xFFFFFFFFull) ^ 0xFFFFFFFFu;
    sel[img * MK + c1 + m] = v;
  }
}

// ---------- sparse loss ----------
__global__ void k_prep(const unsigned* __restrict__ sel, const float* __restrict__ scoremap,
                       const float* __restrict__ gtA, const float* __restrict__ gtB,
                       const float* __restrict__ vA, const float* __restrict__ vB,
                       float* px, float* py, float* wx, float* wy, float* lg, float* sl) {
  int t = blockIdx.x * 256 + threadIdx.x;  // 0..32767
  int img = t >> 11;
  unsigned idx = sel[t] & (HW_ - 1);
  int h = idx >> 9, w = idx & 511;
  px[t] = (w + 0.5f) * (2.0f / 512.0f) - 1.0f;
  py[t] = (h + 0.5f) * (2.0f / 512.0f) - 1.0f;
  int b = (img < 8) ? img : img - 8;
  const float* gt = (img < 8) ? gtA : gtB;
  const float* vv = (img < 8) ? vA : vB;
  size_t pix = (size_t)b * HW_ + idx;
  wx[t] = gt[pix * 4 + 2];
  wy[t] = gt[pix * 4 + 3];
  lg[t] = (vv[pix] > 0.0f) ? 1.0f : 0.0f;
  sl[t] = scoremap[(size_t)img * HW_ + idx];
}

__global__ void k_mindist(const float* __restrict__ px, const float* __restrict__ py,
                          const float* __restrict__ wx, const float* __restrict__ wy,
                          float* r) {
  __shared__ float ox[MK], oy[MK];
  int img = blockIdx.x >> 3, ch = blockIdx.x & 7;
  int opp = (img < 8) ? img + 8 : img - 8;
  for (int k = threadIdx.x; k < MK; k += 256) {
    ox[k] = px[opp * MK + k];
    oy[k] = py[opp * MK + k];
  }
  __syncthreads();
  int m = img * MK + ch * 256 + threadIdx.x;
  float ax = wx[m], ay = wy[m];
  float d2 = 3.4e38f;
  for (int n = 0; n < MK; n++) {
    float dx = ax - ox[n], dy = ay - oy[n];
    d2 = fminf(d2, dx * dx + dy * dy);
  }
  r[m] = expf(-100.0f * sqrtf(d2 + 1e-12f));
}

__global__ void __launch_bounds__(1024)
k_loss(const float* __restrict__ sl, const float* __restrict__ lg,
       const float* __restrict__ r, float* sacc) {
  int img = blockIdx.x;
  __shared__ float red[1024];
  int t = threadIdx.x;
  int i0 = img * MK + t, i1 = i0 + 1024;
  float s0 = sl[i0], s1 = sl[i1];
  float g0 = lg[i0], g1 = lg[i1];
  float l0 = (g0 > 0.0f) ? s0 : -1e9f;
  float l1 = (g1 > 0.0f) ? s1 : -1e9f;
  float mx = brmax<1024>(fmaxf(l0, l1), red);
  float se = brsum<1024>(expf(l0 - mx) + expf(l1 - mx), red);
  float lse = mx + logf(se);
  float a = 0.0f;
  if (g0 > 0.0f) a += r[i0] * (s0 - lse);
  if (g1 > 0.0f) a += r[i1] * (s1 - lse);
  float tot = brsum<1024>(a, red);
  if (t == 0) atomicAdd(sacc, -tot);
}

__global__ void k_out(const float* macc, const float* sacc, float* out) {
  out[0] = sacc[0] + macc[0] * (1.0f / 16.0f);
}

// ---------- launch ----------
extern "C" void kernel_launch(void* const* d_in, const int* in_sizes, int n_in,
                              void* d_out, int out_size, void* d_ws, size_t ws_size,
                              hipStream_t stream) {
  const float* scoremap = (const float*)d_in[0];
  const float* gtA = (const float*)d_in[1];
  const float* gtB = (const float*)d_in[2];
  const float* vA  = (const float*)d_in[3];
  const float* vB  = (const float*)d_in[4];
  const float* hd  = (const float*)d_in[5];

  char* ws = (char*)d_ws;
  float* A  = (float*)(ws);
  float* B1 = (float*)(ws + OFF_B1);
  float* B2 = (float*)(ws + OFF_B2);

  char* sm = ws + OFF_SMALL;
  float*    sume   = (float*)(sm + 0);      // 16 imgs * 128B each region
  float*    sumS   = (float*)(sm + 2048);
  float*    Zb     = (float*)(sm + 4096);
  unsigned* Tb     = (unsigned*)(sm + 6144);
  unsigned* needb  = (unsigned*)(sm + 8192);
  unsigned* selcnt = (unsigned*)(sm + 10240);
  unsigned* bcnt   = (unsigned*)(sm + 12288);
  float*    macc   = (float*)(sm + 14336);
  float*    sacc   = (float*)(sm + 14464);

  unsigned* hist = (unsigned*)(ws + OFF_HIST);
  unsigned* sel  = (unsigned*)(ws + OFF_SEL);
  unsigned long long* bnd = (unsigned long long*)(ws + OFF_BND);
  float* px = (float*)(ws + OFF_PX);
  float* py = (float*)(ws + OFF_PY);
  float* wx = (float*)(ws + OFF_WXp);
  float* wy = (float*)(ws + OFF_WYp);
  float* lg = (float*)(ws + OFF_LG);
  float* sl = (float*)(ws + OFF_SL);
  float* rr = (float*)(ws + OFF_R);

  float* out = (float*)d_out;

  hipMemsetAsync(sm, 0, 16384, stream);

  // softmax (unnormalized exp in A; sume holds per-image Σexp)
  k_expsum<<<1024, 256, 0, stream>>>(scoremap, A, sume);

  // matchability (hconv also accumulates sumS/Zb via boundary weights)
  k_hconv<<<16384, 256, 0, stream>>>(A, hd, sume, B1, B2, sumS, Zb);
  k_match<<<1024, 256, 0, stream>>>(B1, B2, sumS, Zb, macc);

  // coverage-reweighted scoremap
  k_h51<<<16384, 256, 0, stream>>>(A, sume, B1);
  k_smw<<<1024, 256, 0, stream>>>(A, sume, B1, B2);

  // A is now free: zero histogram region (must be before k_nms which fills it)
  hipMemsetAsync(ws + OFF_HIST, 0, (size_t)16 * 65536 * 4, stream);

  // NMS (+fused hist) + top-k selection
  k_nms<<<1024, 256, 0, stream>>>(B2, B1, hist);
  k_thresh<<<16, 256, 0, stream>>>(hist, Tb, needb);
  k_collect<<<16384, 256, 0, stream>>>(B1, Tb, selcnt, sel, bcnt, bnd);
  k_finsel<<<16, 1024, 0, stream>>>(bnd, bcnt, needb, selcnt, sel);

  // sparse loss
  k_prep<<<128, 256, 0, stream>>>(sel, scoremap, gtA, gtB, vA, vB, px, py, wx, wy, lg, sl);
  k_mindist<<<128, 256, 0, stream>>>(px, py, wx, wy, rr);
  k_loss<<<16, 1024, 0, stream>>>(sl, lg, rr, sacc);

  k_out<<<1, 1, 0, stream>>>(macc, sacc, out);
}

// Round 4
// 576.790 us; speedup vs baseline: 2.1084x; 1.0608x over previous
//
#include <hip/hip_runtime.h>

#define HH 512
#define WW 512
#define HW_ 262144
#define NIMG 16
#define MK 2048
#define CAPB 4096

static constexpr size_t OFF_B1    = 16777216;   // 16MB
static constexpr size_t OFF_B2    = 33554432;   // 32MB
static constexpr size_t OFF_SMALL = 50331648;   // 48MB
// regions inside buffer A (free after smw is computed):
static constexpr size_t OFF_HIST = 0;           // 16*65536*4 = 4MB
static constexpr size_t OFF_SEL  = 4194304;     // 16*2048*4
static constexpr size_t OFF_BND  = 4325376;     // 16*4096*8
static constexpr size_t OFF_PP   = 4849664;     // 32768 float2 = 256KB
static constexpr size_t OFF_WXp  = 5111808;
static constexpr size_t OFF_WYp  = 5242880;
static constexpr size_t OFF_LG   = 5373952;
static constexpr size_t OFF_SL   = 5505024;
static constexpr size_t OFF_R    = 5636096;

// per-image counters padded to 128B (32 u32) to kill cacheline serialization
#define CSTRIDE 32

// ---------- helpers ----------
__device__ __forceinline__ float wred64(float v) {
  for (int m = 1; m < 64; m <<= 1) v += __shfl_xor(v, m);
  return v;
}

// wave-0 computes normalized gaussian-25 into LDS (no barrier here; caller's
// __syncthreads covers visibility)
__device__ __forceinline__ void g25_wave0(float* g) {
  int t = threadIdx.x;
  if (t < 64) {
    float raw = 0.0f;
    if (t < 25) {
      float x = -1.0f + (float)t * (2.0f / 24.0f);
      raw = expf(-(x * x) / 0.5f);
    }
    float s = raw;
    for (int m = 1; m < 64; m <<= 1) s += __shfl_xor(s, m);
    if (t < 25) g[t] = raw / s;
  }
}
// wave-0 computes coverage-51 weights (unnormalized)
__device__ __forceinline__ void w51_wave0(float* wc) {
  int t = threadIdx.x;
  if (t < 51) {
    float x = -2.0f + (float)t * (4.0f / 50.0f);
    wc[t] = expf(-x * x);
  }
}

template<int B>
__device__ __forceinline__ float brsum(float v, float* red) {
  int t = threadIdx.x;
  red[t] = v; __syncthreads();
  for (int s = B >> 1; s > 0; s >>= 1) {
    if (t < s) red[t] += red[t + s];
    __syncthreads();
  }
  float r = red[0]; __syncthreads();
  return r;
}
template<int B>
__device__ __forceinline__ float brmax(float v, float* red) {
  int t = threadIdx.x;
  red[t] = v; __syncthreads();
  for (int s = B >> 1; s > 0; s >>= 1) {
    if (t < s) red[t] = fmaxf(red[t], red[t + s]);
    __syncthreads();
  }
  float r = red[0]; __syncthreads();
  return r;
}

// ---------- pass 1: exp + all three global sums (separable conv trick) ----------
// sume = Σ exp(x); sumS_u = Σ exp(x)*wv(y)*cw(x)  (== Σ of valid-conv output, unnormalized)
// Zb_u = Σ hd*wv(y)*cwp(x)                        (== Σ of padded-conv output)
__global__ void __launch_bounds__(256)
k_pre(const float* __restrict__ x, const float* __restrict__ hd, float* A,
      float* sume, float* sumS, float* Zb) {
  __shared__ float g[25];
  __shared__ float red[12];
  int tid = threadIdx.x;
  g25_wave0(g);
  size_t base = (size_t)blockIdx.x * 1024;
  size_t e = base + tid * 4;
  float4 xs = *(const float4*)(x + e);
  float4 hs = *(const float4*)(hd + e);
  __syncthreads();
  int rem = (int)(e & (HW_ - 1));
  int y = rem >> 9, x0 = rem & 511;
  // wv(y): contribution weight of source row y to padded vertical conv
  float wv = 0.0f;
  {
    int k0 = y - 499; if (k0 < 0) k0 = 0;
    int k1 = y + 12;  if (k1 > 24) k1 = 24;
    for (int k = k0; k <= k1; k++) wv += g[k];
  }
  // cw(i): weight of source col i in row-sum of VALID conv (out cols 12..499)
  float cwv[4], cpv[4];
  {
    int lo = x0 - 487; if (lo < 0) lo = 0;
    int hi = x0;       if (hi > 24) hi = 24;
    float c = 0.0f;
    for (int d = lo; d <= hi; d++) c += g[d];
    cwv[0] = c;
    for (int q = 1; q < 4; q++) {
      int i = x0 + q;
      if (i <= 24) c += g[i];
      if (i >= 488) c -= g[i - 488];
      cwv[q] = c;
    }
  }
  {
    int lo = x0 - 499; if (lo < 0) lo = 0;
    int hi = x0 + 12;  if (hi > 24) hi = 24;
    float c = 0.0f;
    for (int d = lo; d <= hi; d++) c += g[d];
    cpv[0] = c;
    for (int q = 1; q < 4; q++) {
      int i = x0 + q;
      if (i + 12 <= 24) c += g[i + 12];
      if (i >= 500) c -= g[i - 500];
      cpv[q] = c;
    }
  }
  float e0 = expf(xs.x), e1 = expf(xs.y), e2 = expf(xs.z), e3 = expf(xs.w);
  *(float4*)(A + e) = make_float4(e0, e1, e2, e3);
  float r0 = (e0 + e1) + (e2 + e3);
  float r1 = (e0 * cwv[0] + e1 * cwv[1] + e2 * cwv[2] + e3 * cwv[3]) * wv;
  float r2 = (hs.x * cpv[0] + hs.y * cpv[1] + hs.z * cpv[2] + hs.w * cpv[3]) * wv;
  r0 = wred64(r0); r1 = wred64(r1); r2 = wred64(r2);
  int wid = tid >> 6;
  if ((tid & 63) == 0) { red[wid] = r0; red[4 + wid] = r1; red[8 + wid] = r2; }
  __syncthreads();
  if (tid == 0) {
    int img = (int)(base >> 18);
    atomicAdd(&sume[img * CSTRIDE], red[0] + red[1] + red[2] + red[3]);
    atomicAdd(&sumS[img * CSTRIDE], red[4] + red[5] + red[6] + red[7]);
    atomicAdd(&Zb[img * CSTRIDE], red[8] + red[9] + red[10] + red[11]);
  }
}

// ---------- horizontal convs: pure streaming, one row per block ----------
__global__ void __launch_bounds__(256)
k_hconv(const float* __restrict__ A, const float* __restrict__ hd,
        const float* __restrict__ sume, float* b1, float* b2) {
  __shared__ __align__(16) float ta[512];
  __shared__ __align__(16) float th[536];
  __shared__ float g[25];
  int tid = threadIdx.x;
  int blk = blockIdx.x;              // img*512 + row ; blk*512 = flat row offset
  int img = blk >> 9;
  size_t rowoff = (size_t)blk * 512;
  g25_wave0(g);
  ((float2*)ta)[tid] = *(const float2*)(A + rowoff + tid * 2);
  ((float2*)(th + 12))[tid] = *(const float2*)(hd + rowoff + tid * 2);
  if (tid < 12) { th[tid] = 0.0f; th[524 + tid] = 0.0f; }
  __syncthreads();
  float inv = 1.0f / sume[img * CSTRIDE];
  int j = 2 * tid;
  float v1a = 0.0f, v1b = 0.0f;
  if (tid >= 6 && tid <= 249) {      // outputs 12..499 valid, else 0
    float w[26];
#pragma unroll
    for (int d = 0; d < 26; d++) w[d] = ta[j - 12 + d];
#pragma unroll
    for (int d = 0; d < 25; d++) {
      v1a = fmaf(g[d], w[d], v1a);
      v1b = fmaf(g[d], w[d + 1], v1b);
    }
  }
  float v2a = 0.0f, v2b = 0.0f;
  {
    float u[26];
#pragma unroll
    for (int d = 0; d < 26; d++) u[d] = th[j + d];
#pragma unroll
    for (int d = 0; d < 25; d++) {
      v2a = fmaf(g[d], u[d], v2a);
      v2b = fmaf(g[d], u[d + 1], v2b);
    }
  }
  ((float2*)b1)[blk * 256 + tid] = make_float2(v1a * inv, v1b * inv);
  ((float2*)b2)[blk * 256 + tid] = make_float2(v2a, v2b);
}

// fused vertical convs + KL reduction, LDS-tiled (64x64 out, 88x64 in, halo 12)
__global__ void __launch_bounds__(256)
k_match(const float* __restrict__ b1, const float* __restrict__ b2,
        const float* __restrict__ sume, const float* sumS, const float* Zb,
        float* macc) {
  __shared__ float g[25];
  __shared__ float t1[88 * 64];
  __shared__ float t2[88 * 64];
  __shared__ float red4[4];
  g25_wave0(g);
  int blk = blockIdx.x;
  int img = blk >> 6;
  int ty = (blk >> 3) & 7;
  int tx = blk & 7;
  int y0 = ty * 64, x0 = tx * 64;
  const float* base1 = b1 + (size_t)img * HW_;
  const float* base2 = b2 + (size_t)img * HW_;
  for (int i = threadIdx.x; i < 88 * 64; i += 256) {
    int r = i >> 6, c = i & 63;
    int y = y0 + r - 12;
    float v1 = 0.0f, v2 = 0.0f;
    if (y >= 0 && y < 512) {
      size_t o = (size_t)y * 512 + x0 + c;
      v1 = base1[o]; v2 = base2[o];
    }
    t1[i] = v1; t2[i] = v2;
  }
  __syncthreads();
  float Z = Zb[img * CSTRIDE];
  float inv = 1.0f / sume[img * CSTRIDE];
  float logS = logf(sumS[img * CSTRIDE] * inv + (float)HW_ * 1e-8f);
  float acc = 0.0f;
  for (int k0 = 0; k0 < 16; k0++) {
    int i = threadIdx.x + k0 * 256;
    int r = i >> 6, c = i & 63;
    float s = 0.0f, sd = 0.0f;
#pragma unroll
    for (int k = 0; k < 25; k++) {
      s  = fmaf(g[k], t1[(r + k) * 64 + c], s);
      sd = fmaf(g[k], t2[(r + k) * 64 + c], sd);
    }
    float p = sd / Z;
    if (p > 0.0f)
      acc += p * (logf(fmaxf(p, 1e-30f)) - (logf(s + 1e-8f) - logS));
  }
  acc = wred64(acc);
  if ((threadIdx.x & 63) == 0) red4[threadIdx.x >> 6] = acc;
  __syncthreads();
  if (threadIdx.x == 0)
    atomicAdd(macc, red4[0] + red4[1] + red4[2] + red4[3]);
}

// ---------- keypoint sampling ----------
// horizontal 51-tap on (kp+1e-6)*1e4 (normalization folded), one row per block
__global__ void __launch_bounds__(256)
k_h51(const float* __restrict__ A, const float* __restrict__ sume, float* out) {
  __shared__ float wc[51];
  __shared__ __align__(16) float ta[564];
  int tid = threadIdx.x;
  int blk = blockIdx.x;
  int img = blk >> 9;
  size_t rowoff = (size_t)blk * 512;
  w51_wave0(wc);
  float s1 = 1e4f / sume[img * CSTRIDE];
  for (int i = tid; i < 562; i += 256) {
    int j = i - 25;
    ta[i] = ((unsigned)j < 512u) ? fmaf(A[rowoff + j], s1, 1e-2f) : 0.0f;
  }
  __syncthreads();
  int j = 2 * tid;
  float w[52];
#pragma unroll
  for (int d = 0; d < 52; d++) w[d] = ta[j + d];
  float va = 0.0f, vb = 0.0f;
#pragma unroll
  for (int d = 0; d < 51; d++) {
    va = fmaf(wc[d], w[d], va);
    vb = fmaf(wc[d], w[d + 1], vb);
  }
  ((float2*)out)[blk * 256 + tid] = make_float2(va, vb);
}

// vertical 51-tap + coverage reweight, LDS-tiled (64x64 out, 114x64 in, halo 25)
__global__ void __launch_bounds__(256)
k_smw(const float* __restrict__ A, const float* __restrict__ sume,
      const float* __restrict__ b1, float* out) {
  __shared__ float wc[51];
  __shared__ float t[114 * 64];
  w51_wave0(wc);
  int blk = blockIdx.x;
  int img = blk >> 6;
  int ty = (blk >> 3) & 7;
  int tx = blk & 7;
  int y0 = ty * 64, x0 = tx * 64;
  const float* base = b1 + (size_t)img * HW_;
  for (int i = threadIdx.x; i < 114 * 64; i += 256) {
    int r = i >> 6, c = i & 63;
    int y = y0 + r - 25;
    t[i] = (y >= 0 && y < 512) ? base[(size_t)y * 512 + x0 + c] : 0.0f;
  }
  __syncthreads();
  float inv = 1.0f / sume[img * CSTRIDE];
  for (int k0 = 0; k0 < 16; k0++) {
    int i = threadIdx.x + k0 * 256;
    int r = i >> 6, c = i & 63;
    float v = 0.0f;
#pragma unroll
    for (int k = 0; k < 51; k++) v = fmaf(wc[k], t[(r + k) * 64 + c], v);
    size_t o = (size_t)img * HW_ + (size_t)(y0 + r) * 512 + x0 + c;
    out[o] = (A[o] * inv) / sqrtf(v + 1e-8f);
  }
}

// NMS (5x5 max) LDS-tiled + fused histogram of survivors
__global__ void __launch_bounds__(256)
k_nms(const float* __restrict__ in, float* out, unsigned* hist) {
  __shared__ float t[68 * 68];
  int blk = blockIdx.x;
  int img = blk >> 6;
  int ty = (blk >> 3) & 7;
  int tx = blk & 7;
  int y0 = ty * 64, x0 = tx * 64;
  const float* base = in + (size_t)img * HW_;
  for (int i = threadIdx.x; i < 68 * 68; i += 256) {
    int r = i / 68, c = i - r * 68;
    int y = y0 + r - 2, x = x0 + c - 2;
    t[i] = (y >= 0 && y < 512 && x >= 0 && x < 512)
               ? base[(size_t)y * 512 + x] : -3.4e38f;
  }
  __syncthreads();
  for (int k0 = 0; k0 < 16; k0++) {
    int i = threadIdx.x + k0 * 256;
    int r = i >> 6, c = i & 63;
    float v = t[(r + 2) * 68 + (c + 2)];
    float mx = v;
#pragma unroll
    for (int dy = 0; dy < 5; dy++)
#pragma unroll
      for (int dx = 0; dx < 5; dx++)
        mx = fmaxf(mx, t[(r + dy) * 68 + (c + dx)]);
    float res = (v == mx) ? v : 0.0f;
    out[(size_t)img * HW_ + (size_t)(y0 + r) * 512 + x0 + c] = res;
    if (res != 0.0f)
      atomicAdd(&hist[(size_t)img * 65536 + (__float_as_uint(res) >> 16)], 1u);
  }
}

__global__ void k_thresh(const unsigned* __restrict__ hist, unsigned* Tb, unsigned* needb) {
  int img = blockIdx.x;
  const unsigned* h = hist + (size_t)img * 65536;
  __shared__ unsigned part[256];
  __shared__ unsigned scan[257];
  int t = threadIdx.x;
  unsigned s = 0;
  for (int k = 0; k < 256; k++) {
    int bin = 65535 - (t * 256 + k);
    s += (bin == 0) ? 0x00100000u : h[bin];
  }
  part[t] = s; __syncthreads();
  if (t == 0) {
    unsigned c = 0;
    for (int k = 0; k < 256; k++) { scan[k] = c; c += part[k]; }
    scan[256] = c;
  }
  __syncthreads();
  unsigned pre = scan[t];
  if (pre < MK && pre + part[t] >= MK) {
    unsigned c = pre;
    for (int k = 0; k < 256; k++) {
      int bin = 65535 - (t * 256 + k);
      unsigned cnt = (bin == 0) ? 0x00100000u : h[bin];
      if (c + cnt >= MK) { Tb[img * CSTRIDE] = (unsigned)bin; needb[img * CSTRIDE] = MK - c; break; }
      c += cnt;
    }
  }
}

// wave-aggregated compaction
__global__ void k_collect(const float* __restrict__ in, const unsigned* __restrict__ Tb,
                          unsigned* selcnt, unsigned* sel,
                          unsigned* bcnt, unsigned long long* bnd) {
  int t = blockIdx.x * 256 + threadIdx.x;
  int img = t >> 18;
  unsigned idx = (unsigned)(t & (HW_ - 1));
  float v = in[t];
  unsigned bits = __float_as_uint(v);
  unsigned bin = bits >> 16;
  unsigned T = Tb[img * CSTRIDE];
  bool c1 = bin > T;
  bool c2 = bin == T;
  int lane = threadIdx.x & 63;
  unsigned long long lowmask = (1ull << lane) - 1ull;

  unsigned long long m1 = __ballot(c1);
  if (m1) {
    int leader = __ffsll(m1) - 1;
    unsigned base = 0;
    if (lane == leader) base = atomicAdd(&selcnt[img * CSTRIDE], (unsigned)__popcll(m1));
    base = __shfl(base, leader);
    if (c1) {
      unsigned p = base + (unsigned)__popcll(m1 & lowmask);
      if (p < MK) sel[img * MK + p] = idx;
    }
  }
  unsigned long long m2 = __ballot(c2);
  if (m2) {
    int leader = __ffsll(m2) - 1;
    unsigned base = 0;
    if (lane == leader) base = atomicAdd(&bcnt[img * CSTRIDE], (unsigned)__popcll(m2));
    base = __shfl(base, leader);
    if (c2) {
      unsigned p = base + (unsigned)__popcll(m2 & lowmask);
      if (p < CAPB)
        bnd[(size_t)img * CAPB + p] =
            ((unsigned long long)bits << 32) | (unsigned long long)(idx ^ 0xFFFFFFFFu);
    }
  }
}

__global__ void __launch_bounds__(1024)
k_finsel(const unsigned long long* __restrict__ bnd, const unsigned* bcnt,
         const unsigned* needb, const unsigned* selcnt, unsigned* sel) {
  int img = blockIdx.x;
  __shared__ unsigned long long key[CAPB];
  unsigned bn = bcnt[img * CSTRIDE];
  int n = (bn < CAPB) ? (int)bn : CAPB;
  int t = threadIdx.x;
  for (int k = t; k < CAPB; k += 1024)
    key[k] = (k < n) ? bnd[(size_t)img * CAPB + k] : 0ull;
  __syncthreads();
  for (int sz = 2; sz <= CAPB; sz <<= 1) {
    for (int st = sz >> 1; st > 0; st >>= 1) {
      for (int i = t; i < CAPB; i += 1024) {
        int l = i ^ st;
        if (l > i) {
          unsigned long long a = key[i], b = key[l];
          bool up = ((i & sz) == 0);
          if (up ? (a < b) : (a > b)) { key[i] = b; key[l] = a; }
        }
      }
      __syncthreads();
    }
  }
  unsigned c1 = selcnt[img * CSTRIDE]; if (c1 > MK) c1 = MK;
  unsigned need = needb[img * CSTRIDE];
  unsigned kk = need; if (kk > MK - c1) kk = MK - c1;
  for (unsigned m = t; m < MK - c1; m += 1024) {
    unsigned v = 0u;
    if (m < kk && m < (unsigned)n)
      v = (unsigned)(key[m] & 0xFFFFFFFFull) ^ 0xFFFFFFFFu;
    sel[img * MK + c1 + m] = v;
  }
}

// ---------- sparse loss ----------
__global__ void k_prep(const unsigned* __restrict__ sel, const float* __restrict__ scoremap,
                       const float* __restrict__ gtA, const float* __restrict__ gtB,
                       const float* __restrict__ vA, const float* __restrict__ vB,
                       float2* pp, float* wx, float* wy, float* lg, float* sl) {
  int t = blockIdx.x * 256 + threadIdx.x;  // 0..32767
  int img = t >> 11;
  unsigned idx = sel[t] & (HW_ - 1);
  int h = idx >> 9, w = idx & 511;
  pp[t] = make_float2((w + 0.5f) * (2.0f / 512.0f) - 1.0f,
                      (h + 0.5f) * (2.0f / 512.0f) - 1.0f);
  int b = (img < 8) ? img : img - 8;
  const float* gt = (img < 8) ? gtA : gtB;
  const float* vv = (img < 8) ? vA : vB;
  size_t pix = (size_t)b * HW_ + idx;
  wx[t] = gt[pix * 4 + 2];
  wy[t] = gt[pix * 4 + 3];
  lg[t] = (vv[pix] > 0.0f) ? 1.0f : 0.0f;
  sl[t] = scoremap[(size_t)img * HW_ + idx];
}

__global__ void k_mindist(const float2* __restrict__ pp,
                          const float* __restrict__ wx, const float* __restrict__ wy,
                          float* r) {
  __shared__ float2 opp[MK];
  int img = blockIdx.x >> 3, ch = blockIdx.x & 7;
  int oppimg = (img < 8) ? img + 8 : img - 8;
  for (int k = threadIdx.x; k < MK; k += 256)
    opp[k] = pp[oppimg * MK + k];
  __syncthreads();
  int m = img * MK + ch * 256 + threadIdx.x;
  float ax = wx[m], ay = wy[m];
  float d2 = 3.4e38f;
  for (int n = 0; n < MK; n++) {
    float2 o = opp[n];
    float dx = ax - o.x, dy = ay - o.y;
    d2 = fminf(d2, fmaf(dx, dx, dy * dy));
  }
  r[m] = expf(-100.0f * sqrtf(d2 + 1e-12f));
}

__global__ void __launch_bounds__(1024)
k_loss(const float* __restrict__ sl, const float* __restrict__ lg,
       const float* __restrict__ r, float* sacc) {
  int img = blockIdx.x;
  __shared__ float red[1024];
  int t = threadIdx.x;
  int i0 = img * MK + t, i1 = i0 + 1024;
  float s0 = sl[i0], s1 = sl[i1];
  float g0 = lg[i0], g1 = lg[i1];
  float l0 = (g0 > 0.0f) ? s0 : -1e9f;
  float l1 = (g1 > 0.0f) ? s1 : -1e9f;
  float mx = brmax<1024>(fmaxf(l0, l1), red);
  float se = brsum<1024>(expf(l0 - mx) + expf(l1 - mx), red);
  float lse = mx + logf(se);
  float a = 0.0f;
  if (g0 > 0.0f) a += r[i0] * (s0 - lse);
  if (g1 > 0.0f) a += r[i1] * (s1 - lse);
  float tot = brsum<1024>(a, red);
  if (t == 0) atomicAdd(sacc, -tot);
}

__global__ void k_out(const float* macc, const float* sacc, float* out) {
  out[0] = sacc[0] + macc[0] * (1.0f / 16.0f);
}

// ---------- launch ----------
extern "C" void kernel_launch(void* const* d_in, const int* in_sizes, int n_in,
                              void* d_out, int out_size, void* d_ws, size_t ws_size,
                              hipStream_t stream) {
  const float* scoremap = (const float*)d_in[0];
  const float* gtA = (const float*)d_in[1];
  const float* gtB = (const float*)d_in[2];
  const float* vA  = (const float*)d_in[3];
  const float* vB  = (const float*)d_in[4];
  const float* hd  = (const float*)d_in[5];

  char* ws = (char*)d_ws;
  float* A  = (float*)(ws);
  float* B1 = (float*)(ws + OFF_B1);
  float* B2 = (float*)(ws + OFF_B2);

  char* sm = ws + OFF_SMALL;
  float*    sume   = (float*)(sm + 0);      // per-image, stride 128B
  float*    sumS   = (float*)(sm + 2048);
  float*    Zb     = (float*)(sm + 4096);
  unsigned* Tb     = (unsigned*)(sm + 6144);
  unsigned* needb  = (unsigned*)(sm + 8192);
  unsigned* selcnt = (unsigned*)(sm + 10240);
  unsigned* bcnt   = (unsigned*)(sm + 12288);
  float*    macc   = (float*)(sm + 14336);
  float*    sacc   = (float*)(sm + 14464);

  unsigned* hist = (unsigned*)(ws + OFF_HIST);
  unsigned* sel  = (unsigned*)(ws + OFF_SEL);
  unsigned long long* bnd = (unsigned long long*)(ws + OFF_BND);
  float2* pp = (float2*)(ws + OFF_PP);
  float* wx = (float*)(ws + OFF_WXp);
  float* wy = (float*)(ws + OFF_WYp);
  float* lg = (float*)(ws + OFF_LG);
  float* sl = (float*)(ws + OFF_SL);
  float* rr = (float*)(ws + OFF_R);

  float* out = (float*)d_out;

  hipMemsetAsync(sm, 0, 16384, stream);

  // pass 1: exp + sume/sumS/Zb (separable conv sums)
  k_pre<<<4096, 256, 0, stream>>>(scoremap, hd, A, sume, sumS, Zb);

  // matchability
  k_hconv<<<8192, 256, 0, stream>>>(A, hd, sume, B1, B2);
  k_match<<<1024, 256, 0, stream>>>(B1, B2, sume, sumS, Zb, macc);

  // coverage-reweighted scoremap
  k_h51<<<8192, 256, 0, stream>>>(A, sume, B1);
  k_smw<<<1024, 256, 0, stream>>>(A, sume, B1, B2);

  // A is now free: zero histogram region (before k_nms fills it)
  hipMemsetAsync(ws + OFF_HIST, 0, (size_t)16 * 65536 * 4, stream);

  // NMS (+fused hist) + top-k selection
  k_nms<<<1024, 256, 0, stream>>>(B2, B1, hist);
  k_thresh<<<16, 256, 0, stream>>>(hist, Tb, needb);
  k_collect<<<16384, 256, 0, stream>>>(B1, Tb, selcnt, sel, bcnt, bnd);
  k_finsel<<<16, 1024, 0, stream>>>(bnd, bcnt, needb, selcnt, sel);

  // sparse loss
  k_prep<<<128, 256, 0, stream>>>(sel, scoremap, gtA, gtB, vA, vB, pp, wx, wy, lg, sl);
  k_mindist<<<128, 256, 0, stream>>>(pp, wx, wy, rr);
  k_loss<<<16, 1024, 0, stream>>>(sl, lg, rr, sacc);

  k_out<<<1, 1, 0, stream>>>(macc, sacc, out);
}

// Round 5
// 367.784 us; speedup vs baseline: 3.3065x; 1.5683x over previous
//
#include <hip/hip_runtime.h>

#define HH 512
#define WW 512
#define HW_ 262144
#define NIMG 16
#define MK 2048
#define CAPB 4096
#define SCAP 32768   // survivor capacity per image

static constexpr size_t OFF_B1    = 16777216;   // 16MB
static constexpr size_t OFF_B2    = 33554432;   // 32MB
static constexpr size_t OFF_SMALL = 50331648;   // 48MB
// regions inside buffer A (free after smw is computed):
static constexpr size_t OFF_HIST = 0;           // 16*65536*4 = 4MB
static constexpr size_t OFF_SEL  = 4194304;     // 16*2048*4
static constexpr size_t OFF_BND  = 4325376;     // 16*4096*8
static constexpr size_t OFF_PP   = 4849664;     // 32768 float2 = 256KB
static constexpr size_t OFF_WXp  = 5111808;
static constexpr size_t OFF_WYp  = 5242880;
static constexpr size_t OFF_LG   = 5373952;
static constexpr size_t OFF_SL   = 5505024;
static constexpr size_t OFF_PMIN = 5636096;     // 4*32768 floats = 512KB
static constexpr size_t OFF_SURV = 8388608;     // 16*32768*8 = 4MB

// per-image counters padded to 128B (32 u32) to kill cacheline serialization
#define CSTRIDE 32

// ---------- helpers ----------
__device__ __forceinline__ float wred64(float v) {
  for (int m = 1; m < 64; m <<= 1) v += __shfl_xor(v, m);
  return v;
}

// wave-0 computes normalized gaussian-25 into LDS (no barrier here; caller's
// __syncthreads covers visibility)
__device__ __forceinline__ void g25_wave0(float* g) {
  int t = threadIdx.x;
  if (t < 64) {
    float raw = 0.0f;
    if (t < 25) {
      float x = -1.0f + (float)t * (2.0f / 24.0f);
      raw = expf(-(x * x) / 0.5f);
    }
    float s = raw;
    for (int m = 1; m < 64; m <<= 1) s += __shfl_xor(s, m);
    if (t < 25) g[t] = raw / s;
  }
}
// wave-0 computes coverage-51 weights (unnormalized)
__device__ __forceinline__ void w51_wave0(float* wc) {
  int t = threadIdx.x;
  if (t < 51) {
    float x = -2.0f + (float)t * (4.0f / 50.0f);
    wc[t] = expf(-x * x);
  }
}

template<int B>
__device__ __forceinline__ float brsum(float v, float* red) {
  int t = threadIdx.x;
  red[t] = v; __syncthreads();
  for (int s = B >> 1; s > 0; s >>= 1) {
    if (t < s) red[t] += red[t + s];
    __syncthreads();
  }
  float r = red[0]; __syncthreads();
  return r;
}
template<int B>
__device__ __forceinline__ float brmax(float v, float* red) {
  int t = threadIdx.x;
  red[t] = v; __syncthreads();
  for (int s = B >> 1; s > 0; s >>= 1) {
    if (t < s) red[t] = fmaxf(red[t], red[t + s]);
    __syncthreads();
  }
  float r = red[0]; __syncthreads();
  return r;
}

// ---------- pass 1: exp + all three global sums (separable conv trick) ----------
__global__ void __launch_bounds__(256)
k_pre(const float* __restrict__ x, const float* __restrict__ hd, float* A,
      float* sume, float* sumS, float* Zb) {
  __shared__ float g[25];
  __shared__ float red[12];
  int tid = threadIdx.x;
  g25_wave0(g);
  size_t base = (size_t)blockIdx.x * 1024;
  size_t e = base + tid * 4;
  float4 xs = *(const float4*)(x + e);
  float4 hs = *(const float4*)(hd + e);
  __syncthreads();
  int rem = (int)(e & (HW_ - 1));
  int y = rem >> 9, x0 = rem & 511;
  float wv = 0.0f;
  {
    int k0 = y - 499; if (k0 < 0) k0 = 0;
    int k1 = y + 12;  if (k1 > 24) k1 = 24;
    for (int k = k0; k <= k1; k++) wv += g[k];
  }
  float cwv[4], cpv[4];
  {
    int lo = x0 - 487; if (lo < 0) lo = 0;
    int hi = x0;       if (hi > 24) hi = 24;
    float c = 0.0f;
    for (int d = lo; d <= hi; d++) c += g[d];
    cwv[0] = c;
    for (int q = 1; q < 4; q++) {
      int i = x0 + q;
      if (i <= 24) c += g[i];
      if (i >= 488) c -= g[i - 488];
      cwv[q] = c;
    }
  }
  {
    int lo = x0 - 499; if (lo < 0) lo = 0;
    int hi = x0 + 12;  if (hi > 24) hi = 24;
    float c = 0.0f;
    for (int d = lo; d <= hi; d++) c += g[d];
    cpv[0] = c;
    for (int q = 1; q < 4; q++) {
      int i = x0 + q;
      if (i + 12 <= 24) c += g[i + 12];
      if (i >= 500) c -= g[i - 500];
      cpv[q] = c;
    }
  }
  float e0 = expf(xs.x), e1 = expf(xs.y), e2 = expf(xs.z), e3 = expf(xs.w);
  *(float4*)(A + e) = make_float4(e0, e1, e2, e3);
  float r0 = (e0 + e1) + (e2 + e3);
  float r1 = (e0 * cwv[0] + e1 * cwv[1] + e2 * cwv[2] + e3 * cwv[3]) * wv;
  float r2 = (hs.x * cpv[0] + hs.y * cpv[1] + hs.z * cpv[2] + hs.w * cpv[3]) * wv;
  r0 = wred64(r0); r1 = wred64(r1); r2 = wred64(r2);
  int wid = tid >> 6;
  if ((tid & 63) == 0) { red[wid] = r0; red[4 + wid] = r1; red[8 + wid] = r2; }
  __syncthreads();
  if (tid == 0) {
    int img = (int)(base >> 18);
    atomicAdd(&sume[img * CSTRIDE], red[0] + red[1] + red[2] + red[3]);
    atomicAdd(&sumS[img * CSTRIDE], red[4] + red[5] + red[6] + red[7]);
    atomicAdd(&Zb[img * CSTRIDE], red[8] + red[9] + red[10] + red[11]);
  }
}

// ---------- horizontal convs: pure streaming, one row per block ----------
__global__ void __launch_bounds__(256)
k_hconv(const float* __restrict__ A, const float* __restrict__ hd,
        const float* __restrict__ sume, float* b1, float* b2) {
  __shared__ __align__(16) float ta[512];
  __shared__ __align__(16) float th[536];
  __shared__ float g[25];
  int tid = threadIdx.x;
  int blk = blockIdx.x;
  int img = blk >> 9;
  size_t rowoff = (size_t)blk * 512;
  g25_wave0(g);
  ((float2*)ta)[tid] = *(const float2*)(A + rowoff + tid * 2);
  ((float2*)(th + 12))[tid] = *(const float2*)(hd + rowoff + tid * 2);
  if (tid < 12) { th[tid] = 0.0f; th[524 + tid] = 0.0f; }
  __syncthreads();
  float inv = 1.0f / sume[img * CSTRIDE];
  int j = 2 * tid;
  float v1a = 0.0f, v1b = 0.0f;
  if (tid >= 6 && tid <= 249) {
    float w[26];
#pragma unroll
    for (int d = 0; d < 26; d++) w[d] = ta[j - 12 + d];
#pragma unroll
    for (int d = 0; d < 25; d++) {
      v1a = fmaf(g[d], w[d], v1a);
      v1b = fmaf(g[d], w[d + 1], v1b);
    }
  }
  float v2a = 0.0f, v2b = 0.0f;
  {
    float u[26];
#pragma unroll
    for (int d = 0; d < 26; d++) u[d] = th[j + d];
#pragma unroll
    for (int d = 0; d < 25; d++) {
      v2a = fmaf(g[d], u[d], v2a);
      v2b = fmaf(g[d], u[d + 1], v2b);
    }
  }
  ((float2*)b1)[blk * 256 + tid] = make_float2(v1a * inv, v1b * inv);
  ((float2*)b2)[blk * 256 + tid] = make_float2(v2a, v2b);
}

// fused vertical convs + KL reduction, LDS-tiled
__global__ void __launch_bounds__(256)
k_match(const float* __restrict__ b1, const float* __restrict__ b2,
        const float* __restrict__ sume, const float* sumS, const float* Zb,
        float* macc) {
  __shared__ float g[25];
  __shared__ float t1[88 * 64];
  __shared__ float t2[88 * 64];
  __shared__ float red4[4];
  g25_wave0(g);
  int blk = blockIdx.x;
  int img = blk >> 6;
  int ty = (blk >> 3) & 7;
  int tx = blk & 7;
  int y0 = ty * 64, x0 = tx * 64;
  const float* base1 = b1 + (size_t)img * HW_;
  const float* base2 = b2 + (size_t)img * HW_;
  for (int i = threadIdx.x; i < 88 * 64; i += 256) {
    int r = i >> 6, c = i & 63;
    int y = y0 + r - 12;
    float v1 = 0.0f, v2 = 0.0f;
    if (y >= 0 && y < 512) {
      size_t o = (size_t)y * 512 + x0 + c;
      v1 = base1[o]; v2 = base2[o];
    }
    t1[i] = v1; t2[i] = v2;
  }
  __syncthreads();
  float Z = Zb[img * CSTRIDE];
  float inv = 1.0f / sume[img * CSTRIDE];
  float logS = logf(sumS[img * CSTRIDE] * inv + (float)HW_ * 1e-8f);
  float acc = 0.0f;
  for (int k0 = 0; k0 < 16; k0++) {
    int i = threadIdx.x + k0 * 256;
    int r = i >> 6, c = i & 63;
    float s = 0.0f, sd = 0.0f;
#pragma unroll
    for (int k = 0; k < 25; k++) {
      s  = fmaf(g[k], t1[(r + k) * 64 + c], s);
      sd = fmaf(g[k], t2[(r + k) * 64 + c], sd);
    }
    float p = sd / Z;
    if (p > 0.0f)
      acc += p * (logf(fmaxf(p, 1e-30f)) - (logf(s + 1e-8f) - logS));
  }
  acc = wred64(acc);
  if ((threadIdx.x & 63) == 0) red4[threadIdx.x >> 6] = acc;
  __syncthreads();
  if (threadIdx.x == 0)
    atomicAdd(macc, red4[0] + red4[1] + red4[2] + red4[3]);
}

// ---------- keypoint sampling ----------
__global__ void __launch_bounds__(256)
k_h51(const float* __restrict__ A, const float* __restrict__ sume, float* out) {
  __shared__ float wc[51];
  __shared__ __align__(16) float ta[564];
  int tid = threadIdx.x;
  int blk = blockIdx.x;
  int img = blk >> 9;
  size_t rowoff = (size_t)blk * 512;
  w51_wave0(wc);
  float s1 = 1e4f / sume[img * CSTRIDE];
  for (int i = tid; i < 562; i += 256) {
    int j = i - 25;
    ta[i] = ((unsigned)j < 512u) ? fmaf(A[rowoff + j], s1, 1e-2f) : 0.0f;
  }
  __syncthreads();
  int j = 2 * tid;
  float w[52];
#pragma unroll
  for (int d = 0; d < 52; d++) w[d] = ta[j + d];
  float va = 0.0f, vb = 0.0f;
#pragma unroll
  for (int d = 0; d < 51; d++) {
    va = fmaf(wc[d], w[d], va);
    vb = fmaf(wc[d], w[d + 1], vb);
  }
  ((float2*)out)[blk * 256 + tid] = make_float2(va, vb);
}

__global__ void __launch_bounds__(256)
k_smw(const float* __restrict__ A, const float* __restrict__ sume,
      const float* __restrict__ b1, float* out) {
  __shared__ float wc[51];
  __shared__ float t[114 * 64];
  w51_wave0(wc);
  int blk = blockIdx.x;
  int img = blk >> 6;
  int ty = (blk >> 3) & 7;
  int tx = blk & 7;
  int y0 = ty * 64, x0 = tx * 64;
  const float* base = b1 + (size_t)img * HW_;
  for (int i = threadIdx.x; i < 114 * 64; i += 256) {
    int r = i >> 6, c = i & 63;
    int y = y0 + r - 25;
    t[i] = (y >= 0 && y < 512) ? base[(size_t)y * 512 + x0 + c] : 0.0f;
  }
  __syncthreads();
  float inv = 1.0f / sume[img * CSTRIDE];
  for (int k0 = 0; k0 < 16; k0++) {
    int i = threadIdx.x + k0 * 256;
    int r = i >> 6, c = i & 63;
    float v = 0.0f;
#pragma unroll
    for (int k = 0; k < 51; k++) v = fmaf(wc[k], t[(r + k) * 64 + c], v);
    size_t o = (size_t)img * HW_ + (size_t)(y0 + r) * 512 + x0 + c;
    out[o] = (A[o] * inv) / sqrtf(v + 1e-8f);
  }
}

// NMS (5x5 max) LDS-tiled + survivor compaction + histogram (no dense output)
__global__ void __launch_bounds__(256)
k_nms(const float* __restrict__ in, unsigned long long* surv, unsigned* scnt,
      unsigned* hist) {
  __shared__ float t[68 * 68];
  int blk = blockIdx.x;
  int img = blk >> 6;
  int ty = (blk >> 3) & 7;
  int tx = blk & 7;
  int y0 = ty * 64, x0 = tx * 64;
  const float* base = in + (size_t)img * HW_;
  for (int i = threadIdx.x; i < 68 * 68; i += 256) {
    int r = i / 68, c = i - r * 68;
    int y = y0 + r - 2, x = x0 + c - 2;
    t[i] = (y >= 0 && y < 512 && x >= 0 && x < 512)
               ? base[(size_t)y * 512 + x] : -3.4e38f;
  }
  __syncthreads();
  int lane = threadIdx.x & 63;
  unsigned long long lowmask = (1ull << lane) - 1ull;
  for (int k0 = 0; k0 < 16; k0++) {
    int i = threadIdx.x + k0 * 256;
    int r = i >> 6, c = i & 63;
    float v = t[(r + 2) * 68 + (c + 2)];
    float mx = v;
#pragma unroll
    for (int dy = 0; dy < 5; dy++)
#pragma unroll
      for (int dx = 0; dx < 5; dx++)
        mx = fmaxf(mx, t[(r + dy) * 68 + (c + dx)]);
    bool keep = (v == mx) && (v != 0.0f);
    unsigned long long mkv = __ballot(keep);
    if (mkv) {
      int leader = __ffsll(mkv) - 1;
      unsigned basep = 0;
      if (lane == leader)
        basep = atomicAdd(&scnt[img * CSTRIDE], (unsigned)__popcll(mkv));
      basep = __shfl(basep, leader);
      if (keep) {
        unsigned bits = __float_as_uint(v);
        unsigned idx = (unsigned)((y0 + r) * 512 + x0 + c);
        unsigned p = basep + (unsigned)__popcll(mkv & lowmask);
        if (p < SCAP)
          surv[(size_t)img * SCAP + p] =
              ((unsigned long long)bits << 32) | (unsigned long long)(idx ^ 0xFFFFFFFFu);
        atomicAdd(&hist[(size_t)img * 65536 + (bits >> 16)], 1u);
      }
    }
  }
}

__global__ void k_thresh(const unsigned* __restrict__ hist, unsigned* Tb, unsigned* needb) {
  int img = blockIdx.x;
  const unsigned* h = hist + (size_t)img * 65536;
  __shared__ unsigned part[256];
  __shared__ unsigned scan[257];
  int t = threadIdx.x;
  unsigned s = 0;
  for (int k = 0; k < 256; k++) {
    int bin = 65535 - (t * 256 + k);
    s += (bin == 0) ? 0x00100000u : h[bin];
  }
  part[t] = s; __syncthreads();
  if (t == 0) {
    unsigned c = 0;
    for (int k = 0; k < 256; k++) { scan[k] = c; c += part[k]; }
    scan[256] = c;
  }
  __syncthreads();
  unsigned pre = scan[t];
  if (pre < MK && pre + part[t] >= MK) {
    unsigned c = pre;
    for (int k = 0; k < 256; k++) {
      int bin = 65535 - (t * 256 + k);
      unsigned cnt = (bin == 0) ? 0x00100000u : h[bin];
      if (c + cnt >= MK) { Tb[img * CSTRIDE] = (unsigned)bin; needb[img * CSTRIDE] = MK - c; break; }
      c += cnt;
    }
  }
}

// compaction from survivor list (not the dense map)
__global__ void k_collect(const unsigned long long* __restrict__ surv,
                          const unsigned* __restrict__ scnt,
                          const unsigned* __restrict__ Tb,
                          unsigned* selcnt, unsigned* sel,
                          unsigned* bcnt, unsigned long long* bnd) {
  int blk = blockIdx.x;
  int img = blk >> 7;               // 128 blocks per image
  int i = (blk & 127) * 256 + threadIdx.x;
  unsigned cnt = scnt[img * CSTRIDE]; if (cnt > SCAP) cnt = SCAP;
  unsigned long long entry = ((unsigned)i < cnt) ? surv[(size_t)img * SCAP + i] : 0ull;
  unsigned bits = (unsigned)(entry >> 32);
  unsigned bin = bits >> 16;
  unsigned T = Tb[img * CSTRIDE];
  bool ok = (unsigned)i < cnt;
  bool c1 = ok && (bin > T);
  bool c2 = ok && (bin == T);
  int lane = threadIdx.x & 63;
  unsigned long long lowmask = (1ull << lane) - 1ull;

  unsigned long long m1 = __ballot(c1);
  if (m1) {
    int leader = __ffsll(m1) - 1;
    unsigned base = 0;
    if (lane == leader) base = atomicAdd(&selcnt[img * CSTRIDE], (unsigned)__popcll(m1));
    base = __shfl(base, leader);
    if (c1) {
      unsigned p = base + (unsigned)__popcll(m1 & lowmask);
      if (p < MK) sel[img * MK + p] = (unsigned)(entry & 0xFFFFFFFFull) ^ 0xFFFFFFFFu;
    }
  }
  unsigned long long m2 = __ballot(c2);
  if (m2) {
    int leader = __ffsll(m2) - 1;
    unsigned base = 0;
    if (lane == leader) base = atomicAdd(&bcnt[img * CSTRIDE], (unsigned)__popcll(m2));
    base = __shfl(base, leader);
    if (c2) {
      unsigned p = base + (unsigned)__popcll(m2 & lowmask);
      if (p < CAPB) bnd[(size_t)img * CAPB + p] = entry;
    }
  }
}

__global__ void __launch_bounds__(1024)
k_finsel(const unsigned long long* __restrict__ bnd, const unsigned* bcnt,
         const unsigned* needb, const unsigned* selcnt, unsigned* sel) {
  int img = blockIdx.x;
  __shared__ unsigned long long key[CAPB];
  unsigned bn = bcnt[img * CSTRIDE];
  int n = (bn < CAPB) ? (int)bn : CAPB;
  int np2 = 2;
  while (np2 < n) np2 <<= 1;        // uniform across block
  int t = threadIdx.x;
  for (int k = t; k < np2; k += 1024)
    key[k] = (k < n) ? bnd[(size_t)img * CAPB + k] : 0ull;
  __syncthreads();
  for (int sz = 2; sz <= np2; sz <<= 1) {
    for (int st = sz >> 1; st > 0; st >>= 1) {
      for (int i = t; i < np2; i += 1024) {
        int l = i ^ st;
        if (l > i) {
          unsigned long long a = key[i], b = key[l];
          bool up = ((i & sz) == 0);
          if (up ? (a < b) : (a > b)) { key[i] = b; key[l] = a; }
        }
      }
      __syncthreads();
    }
  }
  unsigned c1 = selcnt[img * CSTRIDE]; if (c1 > MK) c1 = MK;
  unsigned need = needb[img * CSTRIDE];
  unsigned kk = need; if (kk > MK - c1) kk = MK - c1;
  for (unsigned m = t; m < MK - c1; m += 1024) {
    unsigned v = 0u;
    if (m < kk && m < (unsigned)n)
      v = (unsigned)(key[m] & 0xFFFFFFFFull) ^ 0xFFFFFFFFu;
    sel[img * MK + c1 + m] = v;
  }
}

// ---------- sparse loss ----------
__global__ void k_prep(const unsigned* __restrict__ sel, const float* __restrict__ scoremap,
                       const float* __restrict__ gtA, const float* __restrict__ gtB,
                       const float* __restrict__ vA, const float* __restrict__ vB,
                       float2* pp, float* wx, float* wy, float* lg, float* sl) {
  int t = blockIdx.x * 256 + threadIdx.x;  // 0..32767
  int img = t >> 11;
  unsigned idx = sel[t] & (HW_ - 1);
  int h = idx >> 9, w = idx & 511;
  pp[t] = make_float2((w + 0.5f) * (2.0f / 512.0f) - 1.0f,
                      (h + 0.5f) * (2.0f / 512.0f) - 1.0f);
  int b = (img < 8) ? img : img - 8;
  const float* gt = (img < 8) ? gtA : gtB;
  const float* vv = (img < 8) ? vA : vB;
  size_t pix = (size_t)b * HW_ + idx;
  float2 gxy = *(const float2*)(gt + pix * 4 + 2);
  wx[t] = gxy.x;
  wy[t] = gxy.y;
  lg[t] = (vv[pix] > 0.0f) ? 1.0f : 0.0f;
  sl[t] = scoremap[(size_t)img * HW_ + idx];
}

// split 4-way over opponents, 8 independent min accumulators per thread
__global__ void __launch_bounds__(256)
k_mindist(const float2* __restrict__ pp,
          const float* __restrict__ wx, const float* __restrict__ wy,
          float* pmin) {
  __shared__ float2 opp[512];
  int blk = blockIdx.x;            // img(4b)<<5 | qc(3b)<<2 | oc(2b)
  int img = blk >> 5;
  int qc = (blk >> 2) & 7;
  int oc = blk & 3;
  const float2* ob = pp + (size_t)(img ^ 8) * MK + oc * 512;
  for (int k = threadIdx.x; k < 512; k += 256) opp[k] = ob[k];
  __syncthreads();
  int m = img * MK + qc * 256 + threadIdx.x;
  float ax = wx[m], ay = wy[m];
  float d[8];
#pragma unroll
  for (int u = 0; u < 8; u++) d[u] = 3.4e38f;
  for (int n = 0; n < 512; n += 8) {
#pragma unroll
    for (int u = 0; u < 8; u++) {
      float2 o = opp[n + u];
      float dx = ax - o.x, dy = ay - o.y;
      d[u] = fminf(d[u], fmaf(dx, dx, dy * dy));
    }
  }
  float d2 = fminf(fminf(fminf(d[0], d[1]), fminf(d[2], d[3])),
                   fminf(fminf(d[4], d[5]), fminf(d[6], d[7])));
  pmin[oc * (NIMG * MK) + m] = d2;
}

__global__ void __launch_bounds__(1024)
k_loss(const float* __restrict__ sl, const float* __restrict__ lg,
       const float* __restrict__ pmin, float* sacc) {
  int img = blockIdx.x;
  __shared__ float red[1024];
  int t = threadIdx.x;
  int i0 = img * MK + t, i1 = i0 + 1024;
  float s0 = sl[i0], s1 = sl[i1];
  float g0 = lg[i0], g1 = lg[i1];
  float l0 = (g0 > 0.0f) ? s0 : -1e9f;
  float l1 = (g1 > 0.0f) ? s1 : -1e9f;
  float mx = brmax<1024>(fmaxf(l0, l1), red);
  float se = brsum<1024>(expf(l0 - mx) + expf(l1 - mx), red);
  float lse = mx + logf(se);
  const int ST = NIMG * MK;
  float a = 0.0f;
  if (g0 > 0.0f) {
    float mn = fminf(fminf(pmin[i0], pmin[ST + i0]),
                     fminf(pmin[2 * ST + i0], pmin[3 * ST + i0]));
    float r0 = expf(-100.0f * sqrtf(mn + 1e-12f));
    a += r0 * (s0 - lse);
  }
  if (g1 > 0.0f) {
    float mn = fminf(fminf(pmin[i1], pmin[ST + i1]),
                     fminf(pmin[2 * ST + i1], pmin[3 * ST + i1]));
    float r1 = expf(-100.0f * sqrtf(mn + 1e-12f));
    a += r1 * (s1 - lse);
  }
  float tot = brsum<1024>(a, red);
  if (t == 0) atomicAdd(sacc, -tot);
}

__global__ void k_out(const float* macc, const float* sacc, float* out) {
  out[0] = sacc[0] + macc[0] * (1.0f / 16.0f);
}

// ---------- launch ----------
extern "C" void kernel_launch(void* const* d_in, const int* in_sizes, int n_in,
                              void* d_out, int out_size, void* d_ws, size_t ws_size,
                              hipStream_t stream) {
  const float* scoremap = (const float*)d_in[0];
  const float* gtA = (const float*)d_in[1];
  const float* gtB = (const float*)d_in[2];
  const float* vA  = (const float*)d_in[3];
  const float* vB  = (const float*)d_in[4];
  const float* hd  = (const float*)d_in[5];

  char* ws = (char*)d_ws;
  float* A  = (float*)(ws);
  float* B1 = (float*)(ws + OFF_B1);
  float* B2 = (float*)(ws + OFF_B2);

  char* sm = ws + OFF_SMALL;
  float*    sume   = (float*)(sm + 0);      // per-image, stride 128B
  float*    sumS   = (float*)(sm + 2048);
  float*    Zb     = (float*)(sm + 4096);
  unsigned* Tb     = (unsigned*)(sm + 6144);
  unsigned* needb  = (unsigned*)(sm + 8192);
  unsigned* selcnt = (unsigned*)(sm + 10240);
  unsigned* bcnt   = (unsigned*)(sm + 12288);
  float*    macc   = (float*)(sm + 14336);
  float*    sacc   = (float*)(sm + 14464);
  unsigned* scnt   = (unsigned*)(sm + 14592); // 16*... fits: 14592+2048=16640>16384 -> use 2048-byte region below
  // NOTE: need scnt stride region of 2048B; place at sm+16384 (memset covers 32KB)
  scnt = (unsigned*)(sm + 16384);

  unsigned* hist = (unsigned*)(ws + OFF_HIST);
  unsigned* sel  = (unsigned*)(ws + OFF_SEL);
  unsigned long long* bnd = (unsigned long long*)(ws + OFF_BND);
  float2* pp = (float2*)(ws + OFF_PP);
  float* wx = (float*)(ws + OFF_WXp);
  float* wy = (float*)(ws + OFF_WYp);
  float* lg = (float*)(ws + OFF_LG);
  float* sl = (float*)(ws + OFF_SL);
  float* pmin = (float*)(ws + OFF_PMIN);
  unsigned long long* surv = (unsigned long long*)(ws + OFF_SURV);

  float* out = (float*)d_out;

  hipMemsetAsync(sm, 0, 32768, stream);

  // pass 1: exp + sume/sumS/Zb (separable conv sums)
  k_pre<<<4096, 256, 0, stream>>>(scoremap, hd, A, sume, sumS, Zb);

  // matchability
  k_hconv<<<8192, 256, 0, stream>>>(A, hd, sume, B1, B2);
  k_match<<<1024, 256, 0, stream>>>(B1, B2, sume, sumS, Zb, macc);

  // coverage-reweighted scoremap
  k_h51<<<8192, 256, 0, stream>>>(A, sume, B1);
  k_smw<<<1024, 256, 0, stream>>>(A, sume, B1, B2);

  // A is now free: zero histogram region (before k_nms fills it)
  hipMemsetAsync(ws + OFF_HIST, 0, (size_t)16 * 65536 * 4, stream);

  // NMS (+survivor compaction +hist) + top-k selection
  k_nms<<<1024, 256, 0, stream>>>(B2, surv, scnt, hist);
  k_thresh<<<16, 256, 0, stream>>>(hist, Tb, needb);
  k_collect<<<2048, 256, 0, stream>>>(surv, scnt, Tb, selcnt, sel, bcnt, bnd);
  k_finsel<<<16, 1024, 0, stream>>>(bnd, bcnt, needb, selcnt, sel);

  // sparse loss
  k_prep<<<128, 256, 0, stream>>>(sel, scoremap, gtA, gtB, vA, vB, pp, wx, wy, lg, sl);
  k_mindist<<<512, 256, 0, stream>>>(pp, wx, wy, pmin);
  k_loss<<<16, 1024, 0, stream>>>(sl, lg, pmin, sacc);

  k_out<<<1, 1, 0, stream>>>(macc, sacc, out);
}